// Round 4
// baseline (1228.364 us; speedup 1.0000x reference)
//
#include <hip/hip_runtime.h>
#include <cstdint>
#include <cstddef>

namespace {

constexpr int SEQ_ = 720;
constexpr int N_ = 64;
constexpr int T_ = 1440;
constexpr int P_ = 180;
constexpr int PO_ = 90;
constexpr int D_ = 256;
constexpr int PD_ = P_ * D_;     // 46080
constexpr float EPS_ = 1e-5f;
constexpr int NTILE_ = 39744;

typedef __attribute__((ext_vector_type(8))) short bf16x8;
typedef __attribute__((ext_vector_type(4))) float f32x4;
typedef __attribute__((ext_vector_type(4))) unsigned short u16x4;

__device__ __forceinline__ float gelu_exact(float x) {
  return 0.5f * x * (1.0f + erff(x * 0.70710678118654752f));
}

__device__ __forceinline__ unsigned short f2bf(float x) {
  unsigned int u = __float_as_uint(x);
  u += 0x7FFFu + ((u >> 16) & 1u);   // round-to-nearest-even
  return (unsigned short)(u >> 16);
}

__device__ __forceinline__ float bf2f(unsigned short h) {
  return __uint_as_float(((unsigned int)h) << 16);
}

// ---------------- K1: revin stats ----------------
__global__ __launch_bounds__(256) void revin_stats_kernel(
    const float* __restrict__ hist, const float* __restrict__ rw,
    const float* __restrict__ rb, float* __restrict__ meanA,
    float* __restrict__ stdevA, float* __restrict__ sA, float* __restrict__ sB) {
  int b = blockIdx.x;
  int tid = threadIdx.x;
  int n = tid & 63, c = tid >> 6;
  float s = 0.f, s2 = 0.f;
  for (int l = c; l < SEQ_; l += 4) {
    float v = hist[(size_t)(b * SEQ_ + l) * N_ + n];
    s += v; s2 += v * v;
  }
  __shared__ float rs[4][64], rq[4][64];
  rs[c][n] = s; rq[c][n] = s2;
  __syncthreads();
  if (tid < 64) {
    float S = rs[0][tid] + rs[1][tid] + rs[2][tid] + rs[3][tid];
    float Q = rq[0][tid] + rq[1][tid] + rq[2][tid] + rq[3][tid];
    float mu = S * (1.f / (float)SEQ_);
    float var = Q * (1.f / (float)SEQ_) - mu * mu;
    float sd = sqrtf(var + EPS_);
    int bn = b * 64 + tid;
    meanA[bn] = mu; stdevA[bn] = sd;
    float a = rw[tid] / sd;
    sA[bn] = a;
    sB[bn] = rb[tid] - mu * a;
  }
}

// ---------------- K2: pred matmul (fused revin normalize) ----------------
__global__ __launch_bounds__(256) void pred_kernel(
    const float* __restrict__ hist, const float* __restrict__ predw,
    const float* __restrict__ predb, const float* __restrict__ sA,
    const float* __restrict__ sB, float* __restrict__ xbuf) {
  int b = blockIdx.y;
  int t = blockIdx.x * 32 + (threadIdx.x & 31);
  int ng = threadIdx.x >> 5;
  const float* hb = hist + (size_t)b * SEQ_ * N_ + ng * 8;
  float acc[8] = {0.f,0.f,0.f,0.f,0.f,0.f,0.f,0.f};
  float wsum = 0.f;
  #pragma unroll 4
  for (int l = 0; l < SEQ_; l++) {
    float w = predw[(size_t)l * T_ + t];
    float4 h0 = *reinterpret_cast<const float4*>(hb + (size_t)l * N_);
    float4 h1 = *reinterpret_cast<const float4*>(hb + (size_t)l * N_ + 4);
    acc[0] += h0.x * w; acc[1] += h0.y * w; acc[2] += h0.z * w; acc[3] += h0.w * w;
    acc[4] += h1.x * w; acc[5] += h1.y * w; acc[6] += h1.z * w; acc[7] += h1.w * w;
    wsum += w;
  }
  float pb = predb[t];
  #pragma unroll
  for (int q = 0; q < 8; q++) {
    int bn = b * 64 + ng * 8 + q;
    xbuf[(size_t)bn * T_ + t] = sA[bn] * acc[q] + sB[bn] * wsum + pb;
  }
}

// ---------------- K3: patch embed (+pos emb), bf16 out; mode1 also emits row LN stats ----------------
__global__ __launch_bounds__(256) void embed_kernel(
    const float* __restrict__ src, const float* __restrict__ embw,
    unsigned short* __restrict__ dst, int mode,
    float* __restrict__ muX, float* __restrict__ rsX) {
  __shared__ float Es[16 * 256];
  __shared__ float Ss[128];
  __shared__ float pS[15][4], pQ[15][4];
  int bn = blockIdx.y;
  int p0 = blockIdx.x * 15;
  int tid = threadIdx.x;
  for (int i = tid; i < 16 * 256; i += 256) Es[i] = embw[i];
  if (tid < 128) {
    int t = p0 * 8 + tid;
    float v;
    if (mode == 0) {
      int tc = t < T_ ? t : (T_ - 1);
      v = src[(size_t)bn * T_ + tc];
    } else {
      int tc = t < SEQ_ ? t : (SEQ_ - 1);
      int b = bn >> 6, n = bn & 63;
      v = src[(size_t)(b * SEQ_ + tc) * N_ + n];
    }
    Ss[tid] = v;
  }
  __syncthreads();
  int np = (mode == 0) ? P_ : PO_;
  float dv = expf(-0.035977892078032f * (float)(tid & ~1));
  int w = tid >> 6, l = tid & 63;
  for (int pi = 0; pi < 15; pi++) {
    int p = p0 + pi;
    float acc = 0.f;
    #pragma unroll
    for (int k = 0; k < 16; k++) acc += Ss[pi * 8 + k] * Es[k * 256 + tid];
    float ang = (float)p * dv;
    float pe = (tid & 1) ? cosf(ang) : sinf(ang);
    float ov = acc + pe;
    dst[((size_t)bn * np + p) * D_ + tid] = f2bf(ov);
    if (mode == 1) {
      float s = ov, q = ov * ov;
      #pragma unroll
      for (int off = 32; off > 0; off >>= 1) { s += __shfl_xor(s, off); q += __shfl_xor(q, off); }
      if (l == 0) { pS[pi][w] = s; pQ[pi][w] = q; }
    }
  }
  if (mode == 1) {
    __syncthreads();
    if (tid < 15) {
      float S = pS[tid][0] + pS[tid][1] + pS[tid][2] + pS[tid][3];
      float Q = pQ[tid][0] + pQ[tid][1] + pQ[tid][2] + pQ[tid][3];
      float mu = S * (1.f / 256.f);
      int idx = bn * 90 + p0 + tid;
      muX[idx] = mu;
      rsX[idx] = rsqrtf(Q * (1.f / 256.f) - mu * mu + EPS_);
    }
  }
}

// ---------------- K_conv: ALL weights, 4-way interleaved launches, double-buffered pipeline ----------------
// tile ranges: [0,17280) temp 6x180x16 (256x256 -> 256x256)
//              [17280,31104) chan 6x256x9 (180x180 -> 192x192 padded)
//              [31104,39744) head 720x12 (46080x720 -> 46080x768 padded)
// Interleaved (mod-step) split preserves the temp/chan/head stream MIX per
// launch (round-2 showed type-split costs 3.1 -> 2.15 TB/s) while making each
// dispatch ~1/4 duration so temp/chan_mfma counters surface in rocprof top-5.
struct TileInfo {
  const float* Wg; unsigned short* Og;
  int K, Nn, Kp, k0, n0;
};

__device__ __forceinline__ TileInfo decode_tile(
    int bid,
    const float* t0, const float* t1, const float* t2, const float* t3,
    const float* t4, const float* t5,
    const float* c0, const float* c1, const float* c2, const float* c3,
    const float* c4p, const float* c5, const float* hw,
    unsigned short* WtAll, unsigned short* WcAll, unsigned short* WhAll) {
  TileInfo ti;
  int tk, tn;
  if (bid < 17280) {
    int tt = bid / 2880, rem = bid - tt * 2880;
    int g = rem >> 4, tile = rem & 15;
    const float* s = t0;
    if (tt == 1) s = t1; else if (tt == 2) s = t2; else if (tt == 3) s = t3;
    else if (tt == 4) s = t4; else if (tt == 5) s = t5;
    ti.Wg = s + (size_t)g * 65536;
    ti.Og = WtAll + (size_t)tt * 11796480 + (size_t)g * 65536;
    ti.K = 256; ti.Nn = 256; ti.Kp = 256; tk = tile >> 2; tn = tile & 3;
  } else if (bid < 31104) {
    int b2 = bid - 17280;
    int tt = b2 / 2304, rem = b2 - tt * 2304;
    int g = rem / 9, tile = rem - g * 9;
    const float* s = c0;
    if (tt == 1) s = c1; else if (tt == 2) s = c2; else if (tt == 3) s = c3;
    else if (tt == 4) s = c4p; else if (tt == 5) s = c5;
    ti.Wg = s + (size_t)g * 32400;
    ti.Og = WcAll + (size_t)tt * 9437184 + (size_t)g * 36864;
    ti.K = 180; ti.Nn = 180; ti.Kp = 192; tk = tile / 3; tn = tile - (tile / 3) * 3;
  } else {
    int b2 = bid - 31104;
    ti.Wg = hw; ti.Og = WhAll;
    ti.K = 46080; ti.Nn = 720; ti.Kp = 46080; tk = b2 / 12; tn = b2 - (b2 / 12) * 12;
  }
  ti.k0 = tk * 64; ti.n0 = tn * 64;
  return ti;
}

__global__ __launch_bounds__(256) void convT_all_kernel(
    const float* t0, const float* t1, const float* t2, const float* t3,
    const float* t4, const float* t5,
    const float* c0, const float* c1, const float* c2, const float* c3,
    const float* c4p, const float* c5,
    const float* hw,
    unsigned short* WtAll, unsigned short* WcAll, unsigned short* WhAll,
    int phase, int step) {
  __shared__ float Ts[2][64][65];
  int tid = threadIdx.x;
  int kr = tid >> 4, nc = (tid & 15) * 4;
  int S = gridDim.x * step;

  auto do_load = [&](const TileInfo& ti, float4* r) {
    #pragma unroll
    for (int i = 0; i < 4; i++) {
      int k = ti.k0 + kr + i * 16;
      float4 v = make_float4(0.f, 0.f, 0.f, 0.f);
      if (k < ti.K) {
        int n = ti.n0 + nc;
        if (n + 3 < ti.Nn) {
          v = *reinterpret_cast<const float4*>(ti.Wg + (size_t)k * ti.Nn + n);
        } else {
          if (n + 0 < ti.Nn) v.x = ti.Wg[(size_t)k * ti.Nn + n + 0];
          if (n + 1 < ti.Nn) v.y = ti.Wg[(size_t)k * ti.Nn + n + 1];
          if (n + 2 < ti.Nn) v.z = ti.Wg[(size_t)k * ti.Nn + n + 2];
          if (n + 3 < ti.Nn) v.w = ti.Wg[(size_t)k * ti.Nn + n + 3];
        }
      }
      r[i] = v;
    }
  };

  auto do_write = [&](const float4* r, int b) {
    #pragma unroll
    for (int i = 0; i < 4; i++) {
      Ts[b][kr + i * 16][nc + 0] = r[i].x;
      Ts[b][kr + i * 16][nc + 1] = r[i].y;
      Ts[b][kr + i * 16][nc + 2] = r[i].z;
      Ts[b][kr + i * 16][nc + 3] = r[i].w;
    }
  };

  auto do_store = [&](const TileInfo& ti, int b) {
    #pragma unroll
    for (int it = 0; it < 2; it++) {
      int nr = (tid >> 3) + it * 32;
      int kc = (tid & 7) * 8;
      unsigned int tmp[4];
      #pragma unroll
      for (int j = 0; j < 4; j++) {
        unsigned int lo = f2bf(Ts[b][kc + 2 * j][nr]);
        unsigned int hi = f2bf(Ts[b][kc + 2 * j + 1][nr]);
        tmp[j] = lo | (hi << 16);
      }
      uint4 vv; vv.x = tmp[0]; vv.y = tmp[1]; vv.z = tmp[2]; vv.w = tmp[3];
      *reinterpret_cast<uint4*>(ti.Og + (size_t)(ti.n0 + nr) * ti.Kp + ti.k0 + kc) = vv;
    }
  };

#define DECODE(tt) decode_tile((tt), t0,t1,t2,t3,t4,t5, c0,c1,c2,c3,c4p,c5, hw, WtAll, WcAll, WhAll)

  int t = phase + blockIdx.x * step;
  if (t >= NTILE_) return;

  float4 rA[4], rB[4];
  TileInfo i0 = DECODE(t);
  do_load(i0, rA);
  bool v1 = (t + S < NTILE_);
  TileInfo i1 = v1 ? DECODE(t + S) : i0;
  if (v1) do_load(i1, rB);
  do_write(rA, 0);                         // waits rA (tile t)
  bool v2 = (t + 2 * S < NTILE_);
  TileInfo i2 = v2 ? DECODE(t + 2 * S) : i0;
  if (v2) do_load(i2, rA);                 // reuse rA slot for t+2S
  __syncthreads();

  // Invariant at top of phase A: Ts[0]=tile t (ready); rB=t+S; rA=t+2S (flight)
  while (true) {
    // ---- phase A: tile t from buf 0 ----
    if (v1) do_write(rB, 1);               // waits rB only (oldest loads)
    {
      bool v3 = (t + 3 * S < NTILE_);
      TileInfo i3 = i2;
      if (v3) { i3 = DECODE(t + 3 * S); do_load(i3, rB); }
      do_store(i0, 0);
      __syncthreads();
      t += S;
      if (!v1) return;
      i0 = i1; i1 = i2; i2 = i3; v1 = v2; v2 = v3;
    }
    // ---- phase B: tile t from buf 1 (regs swapped) ----
    if (v1) do_write(rA, 0);
    {
      bool v3 = (t + 3 * S < NTILE_);
      TileInfo i3 = i2;
      if (v3) { i3 = DECODE(t + 3 * S); do_load(i3, rA); }
      do_store(i0, 1);
      __syncthreads();
      t += S;
      if (!v1) return;
      i0 = i1; i1 = i2; i2 = i3; v1 = v2; v2 = v3;
    }
  }
#undef DECODE
}

// ---------------- K4: temp mix MFMA, single-LDS-buffer, early W issue, 4 blocks/CU ----------------
// vs round 3: __launch_bounds__(256,4) (LDS 34.8KB, VGPR target 128), and the
// first W1/W2 fragment loads are issued BEFORE the preceding barrier/VALU phase
// so their HBM/L2 latency hides under staging / GELU instead of being exposed.
__global__ __launch_bounds__(256, 4) void temp_mfma_kernel(
    const unsigned short* __restrict__ X, unsigned short* __restrict__ Y,
    const unsigned short* __restrict__ W1t, const float* __restrict__ B1,
    const unsigned short* __restrict__ W2t, const float* __restrict__ B2,
    const float* __restrict__ NW, const float* __restrict__ NB) {
  __shared__ __align__(16) short Xs[64 * 256];
  __shared__ float partS[64][4];
  __shared__ float partQ[64][4];
  int lin = (blockIdx.x & 7) * 90 + (blockIdx.x >> 3);  // bijective, 720 % 8 == 0
  int p = lin >> 2;
  int m0 = (lin & 3) << 6;
  int tid = threadIdx.x;
  int w = tid >> 6, l = tid & 63;
  int lr = l & 15, lq = l >> 4;
  int n0w = w << 6;

  const unsigned short* W1p = W1t + (size_t)p * 65536;
  const unsigned short* W2p = W2t + (size_t)p * 65536;

  // issue first W1 fragments early — latency hides under X staging + barrier
  bf16x8 bhc[4], bhn[4];
  #pragma unroll
  for (int nf = 0; nf < 4; nf++)
    bhc[nf] = *reinterpret_cast<const bf16x8*>(W1p + (size_t)(n0w + nf * 16 + lr) * 256 + lq * 8);

  const unsigned short* Xblk = X + (size_t)m0 * PD_ + (size_t)p * D_;
  for (int i = tid; i < 64 * 32; i += 256) {
    int r = i >> 5, c8 = (i & 31) << 3;
    uint4 v = *reinterpret_cast<const uint4*>(Xblk + (size_t)r * PD_ + c8);
    *reinterpret_cast<uint4*>(&Xs[r * 256 + (c8 ^ ((r & 7) << 3))]) = v;
  }
  __syncthreads();

  f32x4 zero4 = {0.f, 0.f, 0.f, 0.f};
  f32x4 acc[4][4];
  #pragma unroll
  for (int a = 0; a < 4; a++)
    #pragma unroll
    for (int b = 0; b < 4; b++) acc[a][b] = zero4;

  for (int ks = 0; ks < 8; ks++) {
    int kb = ks * 32 + lq * 8;
    bf16x8 af[4];
    #pragma unroll
    for (int mf = 0; mf < 4; mf++) {
      int r = mf * 16 + lr;
      af[mf] = *reinterpret_cast<const bf16x8*>(&Xs[r * 256 + (kb ^ ((r & 7) << 3))]);
    }
    if (ks < 7) {
      #pragma unroll
      for (int nf = 0; nf < 4; nf++)
        bhn[nf] = *reinterpret_cast<const bf16x8*>(W1p + (size_t)(n0w + nf * 16 + lr) * 256 + kb + 32);
    }
    #pragma unroll
    for (int mf = 0; mf < 4; mf++)
      #pragma unroll
      for (int nf = 0; nf < 4; nf++)
        acc[mf][nf] = __builtin_amdgcn_mfma_f32_16x16x32_bf16(af[mf], bhc[nf], acc[mf][nf], 0, 0, 0);
    if (ks < 7) {
      #pragma unroll
      for (int nf = 0; nf < 4; nf++) bhc[nf] = bhn[nf];
    }
  }

  // issue first W2 fragments now — latency hides under GELU VALU phase
  bf16x8 bh2[4];
  #pragma unroll
  for (int nf = 0; nf < 4; nf++)
    bh2[nf] = *reinterpret_cast<const bf16x8*>(W2p + (size_t)(n0w + nf * 16 + lr) * 256 + lq * 8);

  __syncthreads();   // all waves done reading X from Xs

  // bias + gelu -> overwrite Xs (bf16, swizzled; same pattern GEMM2 expects)
  #pragma unroll
  for (int nf = 0; nf < 4; nf++) {
    int n = n0w + nf * 16 + lr;
    float bias = B1[p * 256 + n];
    #pragma unroll
    for (int mf = 0; mf < 4; mf++)
      #pragma unroll
      for (int rg = 0; rg < 4; rg++) {
        int r = mf * 16 + lq * 4 + rg;
        Xs[r * 256 + (n ^ ((r & 7) << 3))] =
            (short)f2bf(gelu_exact(acc[mf][nf][rg] + bias));
      }
  }
  __syncthreads();

  #pragma unroll
  for (int a = 0; a < 4; a++)
    #pragma unroll
    for (int b = 0; b < 4; b++) acc[a][b] = zero4;
  for (int ks = 0; ks < 8; ks++) {
    int kb = ks * 32 + lq * 8;
    bf16x8 af[4];
    #pragma unroll
    for (int mf = 0; mf < 4; mf++) {
      int r = mf * 16 + lr;
      af[mf] = *reinterpret_cast<const bf16x8*>(&Xs[r * 256 + (kb ^ ((r & 7) << 3))]);
    }
    if (ks < 7) {
      #pragma unroll
      for (int nf = 0; nf < 4; nf++)
        bhn[nf] = *reinterpret_cast<const bf16x8*>(W2p + (size_t)(n0w + nf * 16 + lr) * 256 + kb + 32);
    }
    #pragma unroll
    for (int mf = 0; mf < 4; mf++)
      #pragma unroll
      for (int nf = 0; nf < 4; nf++)
        acc[mf][nf] = __builtin_amdgcn_mfma_f32_16x16x32_bf16(af[mf], bh2[nf], acc[mf][nf], 0, 0, 0);
    if (ks < 7) {
      #pragma unroll
      for (int nf = 0; nf < 4; nf++) bh2[nf] = bhn[nf];
    }
  }

  // epilogue: o = acc + b2 + residual (from global X, exact bf16 bits, cache-hot), fused LN
  float b2v[4], nwv[4], nbv[4];
  #pragma unroll
  for (int nf = 0; nf < 4; nf++) {
    int n = n0w + nf * 16 + lr;
    b2v[nf] = B2[p * 256 + n];
    nwv[nf] = NW[n];
    nbv[nf] = NB[n];
  }
  #pragma unroll
  for (int nf = 0; nf < 4; nf++) {
    int n = n0w + nf * 16 + lr;
    #pragma unroll
    for (int mf = 0; mf < 4; mf++)
      #pragma unroll
      for (int rg = 0; rg < 4; rg++) {
        int r = mf * 16 + lq * 4 + rg;
        float res = bf2f(Xblk[(size_t)r * PD_ + n]);
        acc[mf][nf][rg] += b2v[nf] + res;
      }
  }
  #pragma unroll
  for (int mf = 0; mf < 4; mf++)
    #pragma unroll
    for (int rg = 0; rg < 4; rg++) {
      float s = acc[mf][0][rg] + acc[mf][1][rg] + acc[mf][2][rg] + acc[mf][3][rg];
      float q = acc[mf][0][rg] * acc[mf][0][rg] + acc[mf][1][rg] * acc[mf][1][rg] +
                acc[mf][2][rg] * acc[mf][2][rg] + acc[mf][3][rg] * acc[mf][3][rg];
      #pragma unroll
      for (int off = 1; off < 16; off <<= 1) {
        s += __shfl_xor(s, off);
        q += __shfl_xor(q, off);
      }
      if (lr == 0) {
        int r = mf * 16 + lq * 4 + rg;
        partS[r][w] = s;
        partQ[r][w] = q;
      }
    }
  __syncthreads();   // partS/partQ ready; also all GEMM2 reads of Xs done
  #pragma unroll
  for (int mf = 0; mf < 4; mf++)
    #pragma unroll
    for (int rg = 0; rg < 4; rg++) {
      int r = mf * 16 + lq * 4 + rg;
      float S = partS[r][0] + partS[r][1] + partS[r][2] + partS[r][3];
      float Q = partQ[r][0] + partQ[r][1] + partQ[r][2] + partQ[r][3];
      float mu = S * (1.f / 256.f);
      float rstd = rsqrtf(Q * (1.f / 256.f) - mu * mu + EPS_);
      #pragma unroll
      for (int nf = 0; nf < 4; nf++) {
        int n = n0w + nf * 16 + lr;
        Xs[r * 256 + (n ^ ((r & 7) << 3))] =
            (short)f2bf((acc[mf][nf][rg] - mu) * rstd * nwv[nf] + nbv[nf]);
      }
    }
  __syncthreads();
  unsigned short* Yblk = Y + (size_t)m0 * PD_ + (size_t)p * D_;
  for (int i = tid; i < 64 * 32; i += 256) {
    int r = i >> 5, c8 = (i & 31) << 3;
    uint4 v = *reinterpret_cast<uint4*>(&Xs[r * 256 + (c8 ^ ((r & 7) << 3))]);
    *reinterpret_cast<uint4*>(Yblk + (size_t)r * PD_ + c8) = v;
  }
}

// ---------------- K_trAB: A bf16 [bn*180+p][256] -> B bf16 [bn*256+d][192] ----------------
__global__ __launch_bounds__(256) void tr_AB_kernel(
    const unsigned short* __restrict__ A, unsigned short* __restrict__ B16) {
  __shared__ unsigned short T[32][184];
  int bn = blockIdx.y;
  int d0 = blockIdx.x * 32;
  int tid = threadIdx.x;
  int ld = tid & 31, pw = tid >> 5;
  for (int p = pw; p < 180; p += 8)
    T[ld][p] = A[((size_t)bn * 180 + p) * 256 + d0 + ld];
  __syncthreads();
  unsigned int* Bu = reinterpret_cast<unsigned int*>(B16);
  for (int i = tid; i < 32 * 96; i += 256) {
    int r = i / 96, jj = i - r * 96;
    int p0 = 2 * jj;
    unsigned int lo = (p0 < 180) ? (unsigned int)T[r][p0] : 0u;
    unsigned int hi = (p0 + 1 < 180) ? (unsigned int)T[r][p0 + 1] : 0u;
    Bu[((size_t)bn * 256 + d0 + r) * 96 + jj] = lo | (hi << 16);
  }
}

// ---------------- K5: chan mix MFMA, single-LDS-buffer, early W issue, 4 blocks/CU ----------------
__global__ __launch_bounds__(256, 4) void chan_mfma_kernel(
    const unsigned short* __restrict__ Xb, unsigned short* __restrict__ Yb,
    const unsigned short* __restrict__ W1t, const float* __restrict__ B1,
    const unsigned short* __restrict__ W2t, const float* __restrict__ B2) {
  __shared__ __align__(16) short Xs[64 * 200];
  int lin = (blockIdx.x & 7) * 128 + (blockIdx.x >> 3);  // 1024 % 8 == 0
  int d = lin >> 2;
  int m0 = (lin & 3) << 6;
  int tid = threadIdx.x;
  int w = tid >> 6, l = tid & 63;
  int lr = l & 15, lq = l >> 4;
  int n0w = w * 48;

  const unsigned short* W1p = W1t + (size_t)d * (192 * 192);
  const unsigned short* W2p = W2t + (size_t)d * (192 * 192);

  // issue first W1 fragments early — latency hides under X staging + barrier
  bf16x8 bhc[3], bhn[3];
  #pragma unroll
  for (int nf = 0; nf < 3; nf++)
    bhc[nf] = *reinterpret_cast<const bf16x8*>(W1p + (size_t)(n0w + nf * 16 + lr) * 192 + lq * 8);

  for (int i = tid; i < 64 * 24; i += 256) {
    int r = i / 24, c = i - r * 24;
    uint4 v = *reinterpret_cast<const uint4*>(
        Xb + ((size_t)(m0 + r) * 256 + d) * 192 + c * 8);
    *reinterpret_cast<uint4*>(&Xs[r * 200 + c * 8]) = v;
  }
  __syncthreads();

  f32x4 zero4 = {0.f, 0.f, 0.f, 0.f};
  f32x4 acc[4][3];
  #pragma unroll
  for (int a = 0; a < 4; a++)
    #pragma unroll
    for (int b = 0; b < 3; b++) acc[a][b] = zero4;

  for (int ks = 0; ks < 6; ks++) {
    int kb = ks * 32 + lq * 8;
    bf16x8 af[4];
    #pragma unroll
    for (int mf = 0; mf < 4; mf++)
      af[mf] = *reinterpret_cast<const bf16x8*>(&Xs[(mf * 16 + lr) * 200 + kb]);
    if (ks < 5) {
      #pragma unroll
      for (int nf = 0; nf < 3; nf++)
        bhn[nf] = *reinterpret_cast<const bf16x8*>(W1p + (size_t)(n0w + nf * 16 + lr) * 192 + kb + 32);
    }
    #pragma unroll
    for (int mf = 0; mf < 4; mf++)
      #pragma unroll
      for (int nf = 0; nf < 3; nf++)
        acc[mf][nf] = __builtin_amdgcn_mfma_f32_16x16x32_bf16(af[mf], bhc[nf], acc[mf][nf], 0, 0, 0);
    if (ks < 5) {
      #pragma unroll
      for (int nf = 0; nf < 3; nf++) bhc[nf] = bhn[nf];
    }
  }

  // issue first W2 fragments now — latency hides under GELU VALU phase
  bf16x8 bh2[3];
  #pragma unroll
  for (int nf = 0; nf < 3; nf++)
    bh2[nf] = *reinterpret_cast<const bf16x8*>(W2p + (size_t)(n0w + nf * 16 + lr) * 192 + lq * 8);

  __syncthreads();   // all waves done reading X from Xs

  #pragma unroll
  for (int nf = 0; nf < 3; nf++) {
    int n = n0w + nf * 16 + lr;
    bool valid = n < 180;
    float bias = valid ? B1[d * 180 + n] : 0.f;
    #pragma unroll
    for (int mf = 0; mf < 4; mf++)
      #pragma unroll
      for (int rg = 0; rg < 4; rg++) {
        int r = mf * 16 + lq * 4 + rg;
        float h = valid ? gelu_exact(acc[mf][nf][rg] + bias) : 0.f;
        Xs[r * 200 + n] = (short)f2bf(h);
      }
  }
  __syncthreads();

  #pragma unroll
  for (int a = 0; a < 4; a++)
    #pragma unroll
    for (int b = 0; b < 3; b++) acc[a][b] = zero4;
  for (int ks = 0; ks < 6; ks++) {
    int kb = ks * 32 + lq * 8;
    bf16x8 af[4];
    #pragma unroll
    for (int mf = 0; mf < 4; mf++)
      af[mf] = *reinterpret_cast<const bf16x8*>(&Xs[(mf * 16 + lr) * 200 + kb]);
    if (ks < 5) {
      #pragma unroll
      for (int nf = 0; nf < 3; nf++)
        bhn[nf] = *reinterpret_cast<const bf16x8*>(W2p + (size_t)(n0w + nf * 16 + lr) * 192 + kb + 32);
    }
    #pragma unroll
    for (int mf = 0; mf < 4; mf++)
      #pragma unroll
      for (int nf = 0; nf < 3; nf++)
        acc[mf][nf] = __builtin_amdgcn_mfma_f32_16x16x32_bf16(af[mf], bh2[nf], acc[mf][nf], 0, 0, 0);
    if (ks < 5) {
      #pragma unroll
      for (int nf = 0; nf < 3; nf++) bh2[nf] = bhn[nf];
    }
  }

  #pragma unroll
  for (int nf = 0; nf < 3; nf++) {
    int n = n0w + nf * 16 + lr;
    if (n < 180) {
      float b2v = B2[d * 180 + n];
      #pragma unroll
      for (int mf = 0; mf < 4; mf++)
        #pragma unroll
        for (int rg = 0; rg < 4; rg++) {
          int r = mf * 16 + lq * 4 + rg;
          float res = bf2f(Xb[((size_t)(m0 + r) * 256 + d) * 192 + n]);
          Yb[((size_t)(m0 + r) * 256 + d) * 180 + n] = f2bf(acc[mf][nf][rg] + b2v + res);
        }
    }
  }
}

// ---------------- K_trLN: Yb bf16 -> A bf16 with LN over d, comb fuse, P-stats fold ----------------
__global__ __launch_bounds__(256) void trLN_kernel(
    const unsigned short* __restrict__ Bsrc, unsigned short* __restrict__ A,
    const float* __restrict__ nw, const float* __restrict__ nb,
    const float* __restrict__ cw, const float* __restrict__ cb, int useComb,
    float* __restrict__ muP, float* __restrict__ rsP) {
  __shared__ float Tl[16][260];
  int bn = blockIdx.y;
  int p0 = blockIdx.x * 16;
  int tid = threadIdx.x;
  int j = tid & 15, db = tid >> 4;
  #pragma unroll 4
  for (int it = 0; it < 16; ++it) {
    int dd = it * 16 + db;
    float v = 0.f;
    if (p0 + j < 180)
      v = bf2f(Bsrc[((size_t)(bn * 256) + dd) * 180 + p0 + j]);
    Tl[j][dd] = v;
  }
  __syncthreads();
  int w = tid >> 6, l = tid & 63;
  float scale = 1.f, shift = 0.f;
  if (useComb) { scale = cw[0]; shift = cb[0]; }
  float4 w4 = *reinterpret_cast<const float4*>(nw + l * 4);
  float4 b4 = *reinterpret_cast<const float4*>(nb + l * 4);
  #pragma unroll
  for (int rr = 0; rr < 4; ++rr) {
    int row = w * 4 + rr;
    int p = p0 + row;
    float4 v = *reinterpret_cast<const float4*>(&Tl[row][l * 4]);
    float s = v.x + v.y + v.z + v.w;
    float s2 = v.x*v.x + v.y*v.y + v.z*v.z + v.w*v.w;
    #pragma unroll
    for (int off = 32; off > 0; off >>= 1) { s += __shfl_xor(s, off); s2 += __shfl_xor(s2, off); }
    float mu = s * (1.f/256.f);
    float rstd = rsqrtf(s2 * (1.f/256.f) - mu * mu + EPS_);
    if (p < 180) {
      float o0 = ((v.x - mu) * rstd * w4.x + b4.x) * scale + shift;
      float o1 = ((v.y - mu) * rstd * w4.y + b4.y) * scale + shift;
      float o2 = ((v.z - mu) * rstd * w4.z + b4.z) * scale + shift;
      float o3 = ((v.w - mu) * rstd * w4.w + b4.w) * scale + shift;
      unsigned int w0 = (unsigned int)f2bf(o0) | ((unsigned int)f2bf(o1) << 16);
      unsigned int w1 = (unsigned int)f2bf(o2) | ((unsigned int)f2bf(o3) << 16);
      unsigned int* dst = reinterpret_cast<unsigned int*>(
          A + ((size_t)bn * 180 + p) * 256 + l * 4);
      dst[0] = w0; dst[1] = w1;
      if (useComb && p < 90) {
        float so = o0 + o1 + o2 + o3;
        float qo = o0*o0 + o1*o1 + o2*o2 + o3*o3;
        #pragma unroll
        for (int off = 32; off > 0; off >>= 1) { so += __shfl_xor(so, off); qo += __shfl_xor(qo, off); }
        if (l == 0) {
          float muo = so * (1.f/256.f);
          muP[bn * 90 + p] = muo;
          rsP[bn * 90 + p] = rsqrtf(qo * (1.f/256.f) - muo * muo + EPS_);
        }
      }
    }
  }
}

// ---------------- K8: circular autocorrelation, 2-wave lag split, unroll-4 rotation ----------------
__global__ __launch_bounds__(128, 1) void autocorr_kernel(
    const unsigned short* __restrict__ xoldB, const unsigned short* __restrict__ xcB,
    const float* __restrict__ muX, const float* __restrict__ rsX,
    const float* __restrict__ muP, const float* __restrict__ rsP,
    const float* __restrict__ lnw, const float* __restrict__ lnb,
    float* __restrict__ sqa) {
  __shared__ float PI[46][64];
  __shared__ float RED[2][2][64];
  int bn = blockIdx.x >> 2;
  int tid = threadIdx.x;
  int dl = tid & 63;
  int half = tid >> 6;
  int j0 = half * 23;
  int d = ((blockIdx.x & 3) << 6) + dl;
  float w = lnw[d], bb = lnb[d];
  float v[90], wr[90];

  {
    const unsigned short* col = xcB + (size_t)bn * PD_ + d;
    const float* m = muP + bn * 90;
    const float* rs = rsP + bn * 90;
    #pragma unroll
    for (int p = 0; p < 90; p++)
      v[p] = (bf2f(col[(size_t)p * D_]) - m[p]) * rs[p] * w + bb;
    #pragma unroll
    for (int p = 0; p < 90; p++)
      wr[p] = (half == 0) ? v[p] : v[(p + 23) % 90];
  }
  float den = 0.f;
  #pragma unroll 1
  for (int jt = 0; jt < 24; jt += 4) {
    float c0 = 0.f, c1 = 0.f, c2 = 0.f, c3 = 0.f;
    #pragma unroll
    for (int mm = 0; mm < 90; mm++) {
      float vm = v[mm];
      c0 += vm * wr[mm];
      c1 += vm * ((mm + 1 < 90) ? wr[mm + 1] : wr[mm - 89]);
      c2 += vm * ((mm + 2 < 90) ? wr[mm + 2] : wr[mm - 88]);
      c3 += vm * ((mm + 3 < 90) ? wr[mm + 3] : wr[mm - 87]);
    }
    float cq[4] = {c0, c1, c2, c3};
    #pragma unroll
    for (int q = 0; q < 4; q++) {
      if (jt + q < 23) {
        int lag = j0 + jt + q;
        float piv = fmaxf(cq[q] * 0.10540925533894598f, 0.f);
        PI[lag][dl] = piv;
        float wgt = (lag == 0 || lag == 45) ? 1.f : 2.f;
        den += wgt * piv * piv;
      }
    }
    float t0 = wr[0], t1 = wr[1], t2 = wr[2], t3 = wr[3];
    #pragma unroll
    for (int mm = 0; mm < 86; mm++) wr[mm] = wr[mm + 4];
    wr[86] = t0; wr[87] = t1; wr[88] = t2; wr[89] = t3;
  }

  {
    const unsigned short* col = xoldB + (size_t)bn * (PO_ * D_) + d;
    const float* m = muX + bn * 90;
    const float* rs = rsX + bn * 90;
    #pragma unroll
    for (int p = 0; p < 90; p++)
      v[p] = (bf2f(col[(size_t)p * D_]) - m[p]) * rs[p] * w + bb;
    #pragma unroll
    for (int p = 0; p < 90; p++)
      wr[p] = (half == 0) ? v[p] : v[(p + 23) % 90];
  }
  float num = 0.f;
  #pragma unroll 1
  for (int jt = 0; jt < 24; jt += 4) {
    float c0 = 0.f, c1 = 0.f, c2 = 0.f, c3 = 0.f;
    #pragma unroll
    for (int mm = 0; mm < 90; mm++) {
      float vm = v[mm];
      c0 += vm * wr[mm];
      c1 += vm * ((mm + 1 < 90) ? wr[mm + 1] : wr[mm - 89]);
      c2 += vm * ((mm + 2 < 90) ? wr[mm + 2] : wr[mm - 88]);
      c3 += vm * ((mm + 3 < 90) ? wr[mm + 3] : wr[mm - 87]);
    }
    float cq[4] = {c0, c1, c2, c3};
    #pragma unroll
    for (int q = 0; q < 4; q++) {
      if (jt + q < 23) {
        int lag = j0 + jt + q;
        float xi = fmaxf(cq[q] * 0.10540925533894598f, 0.f);
        float wgt = (lag == 0 || lag == 45) ? 1.f : 2.f;
        num += wgt * xi * PI[lag][dl];
      }
    }
    float t0 = wr[0], t1 = wr[1], t2 = wr[2], t3 = wr[3];
    #pragma unroll
    for (int mm = 0; mm < 86; mm++) wr[mm] = wr[mm + 4];
    wr[86] = t0; wr[87] = t1; wr[88] = t2; wr[89] = t3;
  }
  RED[0][half][dl] = den;
  RED[1][half][dl] = num;
  __syncthreads();
  if (half == 0) {
    float Dn = RED[0][0][dl] + RED[0][1][dl];
    float Nm = RED[1][0][dl] + RED[1][1][dl];
    sqa[bn * D_ + d] = sqrtf(Nm / (Dn + 0.001f));
  }
}

// ---------------- K9: scale by sqrt(alpha), transpose to [bn][d][p], bf16 in/out ----------------
__global__ __launch_bounds__(256) void scale_tr_kernel(
    const unsigned short* __restrict__ Xc, const float* __restrict__ sqa,
    unsigned short* __restrict__ Xt) {
  __shared__ float Ts[32][33];
  int bn = blockIdx.y;
  int pt = blockIdx.x % 6, dt = blockIdx.x / 6;
  int p0 = pt * 32, d0 = dt * 32;
  int tid = threadIdx.x;
  {
    int pr = tid >> 3, c4 = (tid & 7) * 4;
    if (p0 + pr < 180) {
      u16x4 h = *reinterpret_cast<const u16x4*>(
          Xc + ((size_t)bn * 180 + p0 + pr) * 256 + d0 + c4);
      Ts[pr][c4]   = bf2f(h[0]); Ts[pr][c4+1] = bf2f(h[1]);
      Ts[pr][c4+2] = bf2f(h[2]); Ts[pr][c4+3] = bf2f(h[3]);
    }
  }
  __syncthreads();
  {
    int dr = tid >> 3, p4 = (tid & 7) * 4;
    float sc = sqa[bn * D_ + d0 + dr];
    #pragma unroll
    for (int i = 0; i < 4; i++) {
      int pp = p0 + p4 + i;
      if (pp < 180)
        Xt[(size_t)bn * PD_ + (size_t)(d0 + dr) * 180 + pp] = f2bf(Ts[p4 + i][dr] * sc);
    }
  }
}

// ---------------- K10: head GEMM MFMA, K-split 16, A/B prefetch ----------------
__global__ __launch_bounds__(256, 2) void head_mfma_kernel(
    const unsigned short* __restrict__ A, const unsigned short* __restrict__ Bw,
    float* __restrict__ P) {
  __shared__ float Rs[64][65];
  int lin = (blockIdx.x & 7) * 96 + (blockIdx.x >> 3);  // 768 % 8 == 0
  int ks = lin / 48;
  int rem = lin - ks * 48;
  int mt = rem & 3, nt = rem >> 2;
  int m0 = mt << 6, n0 = nt << 6;
  int tid = threadIdx.x;
  int w = tid >> 6, l = tid & 63;
  int lr = l & 15, lq = l >> 4;
  f32x4 zero4 = {0.f, 0.f, 0.f, 0.f};
  f32x4 acc[4][4];
  #pragma unroll
  for (int a = 0; a < 4; a++)
    #pragma unroll
    for (int b = 0; b < 4; b++) acc[a][b] = zero4;

  size_t kbase = (size_t)ks * 2880;
  bf16x8 afc[4], bhc[4], afn[4], bhn[4];
  {
    size_t kb = kbase + (size_t)w * 32 + lq * 8;
    #pragma unroll
    for (int mf = 0; mf < 4; mf++)
      afc[mf] = *reinterpret_cast<const bf16x8*>(A + (size_t)(m0 + mf * 16 + lr) * 46080 + kb);
    #pragma unroll
    for (int nf = 0; nf < 4; nf++)
      bhc[nf] = *reinterpret_cast<const bf16x8*>(Bw + (size_t)(n0 + nf * 16 + lr) * 46080 + kb);
  }
  for (int s = w; s < 90; s += 4) {
    int sn = s + 4;
    if (sn < 90) {
      size_t kb = kbase + (size_t)sn * 32 + lq * 8;
      #pragma unroll
      for (int mf = 0; mf < 4; mf++)
        afn[mf] = *reinterpret_cast<const bf16x8*>(A + (size_t)(m0 + mf * 16 + lr) * 46080 + kb);
      #pragma unroll
      for (int nf = 0; nf < 4; nf++)
        bhn[nf] = *reinterpret_cast<const bf16x8*>(Bw + (size_t)(n0 + nf * 16 + lr) * 46080 + kb);
    }
    #pragma unroll
    for (int mf = 0; mf < 4; mf++)
      #pragma unroll
      for (int nf = 0; nf < 4; nf++)
        acc[mf][nf] = __builtin_amdgcn_mfma_f32_16x16x32_bf16(afc[mf], bhc[nf], acc[mf][nf], 0, 0, 0);
    if (sn < 90) {
      #pragma unroll
      for (int mf = 0; mf < 4; mf++) afc[mf] = afn[mf];
      #pragma unroll
      for (int nf = 0; nf < 4; nf++) bhc[nf] = bhn[nf];
    }
  }
  for (int ww = 0; ww < 4; ww++) {
    if (w == ww) {
      #pragma unroll
      for (int mf = 0; mf < 4; mf++)
        #pragma unroll
        for (int nf = 0; nf < 4; nf++)
          #pragma unroll
          for (int rg = 0; rg < 4; rg++) {
            int r = mf * 16 + lq * 4 + rg, c = nf * 16 + lr;
            if (ww == 0) Rs[r][c] = acc[mf][nf][rg];
            else Rs[r][c] += acc[mf][nf][rg];
          }
    }
    __syncthreads();
  }
  for (int i = tid; i < 64 * 64; i += 256) {
    int r = i >> 6, c = i & 63;
    int n = n0 + c;
    if (n < 720)
      P[((size_t)ks * 256 + m0 + r) * 720 + n] = Rs[r][c];
  }
}

// ---------------- K11: reduce partials + final revin inverse + transpose out ----------------
__global__ __launch_bounds__(256) void final_kernel(
    const float* __restrict__ P, const float* __restrict__ hb,
    const float* __restrict__ rw, const float* __restrict__ rb,
    const float* __restrict__ meanA, const float* __restrict__ stdevA,
    float* __restrict__ out) {
  int gid = blockIdx.x * 256 + threadIdx.x;  // < 184320
  int bn = gid / 720, t = gid - bn * 720;
  float s = 0.f;
  #pragma unroll
  for (int ks = 0; ks < 16; ks++) s += P[(size_t)ks * 184320 + gid];
  s += hb[t];
  int b = bn >> 6, n = bn & 63;
  float val = (s - rb[n]) / (rw[n] + 1e-10f) * stdevA[bn] + meanA[bn];
  out[((size_t)(b * 720 + t)) * 64 + n] = val;
}

}  // namespace

extern "C" void kernel_launch(void* const* d_in, const int* in_sizes, int n_in,
                              void* d_out, int out_size, void* d_ws, size_t ws_size,
                              hipStream_t stream) {
  (void)in_sizes; (void)n_in; (void)out_size; (void)ws_size;
  const float* hist   = (const float*)d_in[0];
  const float* revw   = (const float*)d_in[5];
  const float* revb   = (const float*)d_in[6];
  const float* predw  = (const float*)d_in[7];
  const float* predb  = (const float*)d_in[8];
  const float* embw   = (const float*)d_in[9];
  const float* lnw    = (const float*)d_in[10];
  const float* lnb    = (const float*)d_in[11];
  const float* combw  = (const float*)d_in[12];
  const float* combb  = (const float*)d_in[13];
  const float* headw  = (const float*)d_in[14];
  const float* headb  = (const float*)d_in[15];
  const float* tmd_w1 = (const float*)d_in[16];
  const float* tmd_b1 = (const float*)d_in[17];
  const float* tmd_w2 = (const float*)d_in[18];
  const float* tmd_b2 = (const float*)d_in[19];
  const float* tmd_nw = (const float*)d_in[20];
  const float* tmd_nb = (const float*)d_in[21];
  const float* tmu_w1 = (const float*)d_in[22];
  const float* tmu_b1 = (const float*)d_in[23];
  const float* tmu_w2 = (const float*)d_in[24];
  const float* tmu_b2 = (const float*)d_in[25];
  const float* tmu_nw = (const float*)d_in[26];
  const float* tmu_nb = (const float*)d_in[27];
  const float* cmd_w1 = (const float*)d_in[28];
  const float* cmd_b1 = (const float*)d_in[29];
  const float* cmd_w2 = (const float*)d_in[30];
  const float* cmd_b2 = (const float*)d_in[31];
  const float* cmd_nw = (const float*)d_in[32];
  const float* cmd_nb = (const float*)d_in[33];
  const float* cmu_w1 = (const float*)d_in[34];
  const float* cmu_b1 = (const float*)d_in[35];
  const float* cmu_w2 = (const float*)d_in[36];
  const float* cmu_b2 = (const float*)d_in[37];
  const float* cmu_nw = (const float*)d_in[38];
  const float* cmu_nb = (const float*)d_in[39];

  // ---- workspace layout (no aliasing) ----
  float* ws = (float*)d_ws;
  float* meanA  = ws;                   // 256
  float* stdevA = meanA + 256;          // 256
  float* sA     = stdevA + 256;         // 256
  float* sB     = sA + 256;             // 256
  float* muX    = sB + 256;             // 23040
  float* rsX    = muX + 23040;          // 23040
  float* muP    = rsX + 23040;          // 23040
  float* rsP    = muP + 23040;          // 23040
  float* sqa    = rsP + 23040;          // 65536
  float* xbuf   = sqa + 65536;          // 368640
  unsigned short* xoldB = (unsigned short*)(xbuf + 368640);   // 90*256*256 bf16
  unsigned short* A0    = xoldB + 5898240;                    // 46080*256 bf16
  unsigned short* A1    = A0 + 11796480;
  unsigned short* B16   = A1 + 11796480;                      // 256*256*192 bf16
  unsigned short* Yb    = B16 + 12582912;                     // 256*256*180 bf16
  float* part           = (float*)(Yb + 11796480);            // 16*184320 fp32
  unsigned short* Xtb   = (unsigned short*)(part + 2949120);  // 256*46080 bf16
  unsigned short* WtAll = Xtb + 11796480;                     // 6 * 11796480 bf16
  unsigned short* WcAll = WtAll + 70778880;                   // 6 * 9437184 bf16
  unsigned short* WhAll = WcAll + 56623104;                   // 768*46080 bf16

  constexpr int TW = 180 * 256 * 256, TB = 180 * 256;
  constexpr int CW = 256 * 180 * 180, CB = 256 * 180;
  constexpr size_t TSTR = 11796480, CSTR = 9437184;

  // 4 interleaved launches (t % 4 == phase): same stream mix per launch,
  // ~1/4 duration each so the MFMA kernels surface in rocprof top-5.
  for (int ph = 0; ph < 4; ph++) {
    convT_all_kernel<<<2048, 256, 0, stream>>>(
        tmd_w1 + TW, tmd_w2 + TW, tmu_w1 + TW, tmu_w2 + TW, tmu_w1, tmu_w2,
        cmd_w1 + CW, cmd_w2 + CW, cmu_w1 + CW, cmu_w2 + CW, cmu_w1, cmu_w2,
        headw, WtAll, WcAll, WhAll, ph, 4);
  }

  revin_stats_kernel<<<4, 256, 0, stream>>>(hist, revw, revb, meanA, stdevA, sA, sB);
  pred_kernel<<<dim3(45, 4), 256, 0, stream>>>(hist, predw, predb, sA, sB, xbuf);
  embed_kernel<<<dim3(12, 256), 256, 0, stream>>>(xbuf, embw, A0, 0, nullptr, nullptr);
  embed_kernel<<<dim3(6, 256), 256, 0, stream>>>(hist, embw, xoldB, 1, muX, rsX);

  const float* tB1[3] = {tmd_b1 + TB, tmu_b1 + TB, tmu_b1};
  const float* tB2[3] = {tmd_b2 + TB, tmu_b2 + TB, tmu_b2};
  const float* tNW[3] = {tmd_nw + 256, tmu_nw + 256, tmu_nw};
  const float* tNB[3] = {tmd_nb + 256, tmu_nb + 256, tmu_nb};
  const float* cB1[3] = {cmd_b1 + CB, cmu_b1 + CB, cmu_b1};
  const float* cB2[3] = {cmd_b2 + CB, cmu_b2 + CB, cmu_b2};
  const float* cNW[3] = {cmd_nw + 256, cmu_nw + 256, cmu_nw};
  const float* cNB[3] = {cmd_nb + 256, cmu_nb + 256, cmu_nb};

  for (int li = 0; li < 3; li++) {
    temp_mfma_kernel<<<720, 256, 0, stream>>>(
        A0, A1, WtAll + (size_t)(2 * li) * TSTR, tB1[li],
        WtAll + (size_t)(2 * li + 1) * TSTR, tB2[li], tNW[li], tNB[li]);
    tr_AB_kernel<<<dim3(8, 256), 256, 0, stream>>>(A1, B16);
    chan_mfma_kernel<<<1024, 256, 0, stream>>>(
        B16, Yb, WcAll + (size_t)(2 * li) * CSTR, cB1[li],
        WcAll + (size_t)(2 * li + 1) * CSTR, cB2[li]);
    trLN_kernel<<<dim3(12, 256), 256, 0, stream>>>(Yb, A0, cNW[li], cNB[li],
                                                   combw, combb, li == 2 ? 1 : 0,
                                                   muP, rsP);
  }

  autocorr_kernel<<<1024, 128, 0, stream>>>(xoldB, A0, muX, rsX, muP, rsP, lnw, lnb, sqa);
  scale_tr_kernel<<<dim3(48, 256), 256, 0, stream>>>(A0, sqa, Xtb);
  head_mfma_kernel<<<768, 256, 0, stream>>>(Xtb, WhAll, part);
  final_kernel<<<720, 256, 0, stream>>>(part, headb, revw, revb, meanA, stdevA, (float*)d_out);
}

// Round 5
// 1110.908 us; speedup vs baseline: 1.1057x; 1.1057x over previous
//
#include <hip/hip_runtime.h>
#include <cstdint>
#include <cstddef>

namespace {

constexpr int SEQ_ = 720;
constexpr int N_ = 64;
constexpr int T_ = 1440;
constexpr int P_ = 180;
constexpr int PO_ = 90;
constexpr int D_ = 256;
constexpr int PD_ = P_ * D_;     // 46080
constexpr float EPS_ = 1e-5f;
constexpr int NTILE_ = 39744;

typedef __attribute__((ext_vector_type(8))) short bf16x8;
typedef __attribute__((ext_vector_type(4))) float f32x4;
typedef __attribute__((ext_vector_type(4))) unsigned short u16x4;

__device__ __forceinline__ float gelu_exact(float x) {
  return 0.5f * x * (1.0f + erff(x * 0.70710678118654752f));
}

__device__ __forceinline__ unsigned short f2bf(float x) {
  unsigned int u = __float_as_uint(x);
  u += 0x7FFFu + ((u >> 16) & 1u);   // round-to-nearest-even
  return (unsigned short)(u >> 16);
}

__device__ __forceinline__ float bf2f(unsigned short h) {
  return __uint_as_float(((unsigned int)h) << 16);
}

// ---------------- K1: revin stats ----------------
__global__ __launch_bounds__(256) void revin_stats_kernel(
    const float* __restrict__ hist, const float* __restrict__ rw,
    const float* __restrict__ rb, float* __restrict__ meanA,
    float* __restrict__ stdevA, float* __restrict__ sA, float* __restrict__ sB) {
  int b = blockIdx.x;
  int tid = threadIdx.x;
  int n = tid & 63, c = tid >> 6;
  float s = 0.f, s2 = 0.f;
  for (int l = c; l < SEQ_; l += 4) {
    float v = hist[(size_t)(b * SEQ_ + l) * N_ + n];
    s += v; s2 += v * v;
  }
  __shared__ float rs[4][64], rq[4][64];
  rs[c][n] = s; rq[c][n] = s2;
  __syncthreads();
  if (tid < 64) {
    float S = rs[0][tid] + rs[1][tid] + rs[2][tid] + rs[3][tid];
    float Q = rq[0][tid] + rq[1][tid] + rq[2][tid] + rq[3][tid];
    float mu = S * (1.f / (float)SEQ_);
    float var = Q * (1.f / (float)SEQ_) - mu * mu;
    float sd = sqrtf(var + EPS_);
    int bn = b * 64 + tid;
    meanA[bn] = mu; stdevA[bn] = sd;
    float a = rw[tid] / sd;
    sA[bn] = a;
    sB[bn] = rb[tid] - mu * a;
  }
}

// ---------------- K2: pred matmul (fused revin normalize) ----------------
__global__ __launch_bounds__(256) void pred_kernel(
    const float* __restrict__ hist, const float* __restrict__ predw,
    const float* __restrict__ predb, const float* __restrict__ sA,
    const float* __restrict__ sB, float* __restrict__ xbuf) {
  int b = blockIdx.y;
  int t = blockIdx.x * 32 + (threadIdx.x & 31);
  int ng = threadIdx.x >> 5;
  const float* hb = hist + (size_t)b * SEQ_ * N_ + ng * 8;
  float acc[8] = {0.f,0.f,0.f,0.f,0.f,0.f,0.f,0.f};
  float wsum = 0.f;
  #pragma unroll 4
  for (int l = 0; l < SEQ_; l++) {
    float w = predw[(size_t)l * T_ + t];
    float4 h0 = *reinterpret_cast<const float4*>(hb + (size_t)l * N_);
    float4 h1 = *reinterpret_cast<const float4*>(hb + (size_t)l * N_ + 4);
    acc[0] += h0.x * w; acc[1] += h0.y * w; acc[2] += h0.z * w; acc[3] += h0.w * w;
    acc[4] += h1.x * w; acc[5] += h1.y * w; acc[6] += h1.z * w; acc[7] += h1.w * w;
    wsum += w;
  }
  float pb = predb[t];
  #pragma unroll
  for (int q = 0; q < 8; q++) {
    int bn = b * 64 + ng * 8 + q;
    xbuf[(size_t)bn * T_ + t] = sA[bn] * acc[q] + sB[bn] * wsum + pb;
  }
}

// ---------------- K3: patch embed (+pos emb), bf16 out; mode1 also emits row LN stats ----------------
__global__ __launch_bounds__(256) void embed_kernel(
    const float* __restrict__ src, const float* __restrict__ embw,
    unsigned short* __restrict__ dst, int mode,
    float* __restrict__ muX, float* __restrict__ rsX) {
  __shared__ float Es[16 * 256];
  __shared__ float Ss[128];
  __shared__ float pS[15][4], pQ[15][4];
  int bn = blockIdx.y;
  int p0 = blockIdx.x * 15;
  int tid = threadIdx.x;
  for (int i = tid; i < 16 * 256; i += 256) Es[i] = embw[i];
  if (tid < 128) {
    int t = p0 * 8 + tid;
    float v;
    if (mode == 0) {
      int tc = t < T_ ? t : (T_ - 1);
      v = src[(size_t)bn * T_ + tc];
    } else {
      int tc = t < SEQ_ ? t : (SEQ_ - 1);
      int b = bn >> 6, n = bn & 63;
      v = src[(size_t)(b * SEQ_ + tc) * N_ + n];
    }
    Ss[tid] = v;
  }
  __syncthreads();
  int np = (mode == 0) ? P_ : PO_;
  float dv = expf(-0.035977892078032f * (float)(tid & ~1));
  int w = tid >> 6, l = tid & 63;
  for (int pi = 0; pi < 15; pi++) {
    int p = p0 + pi;
    float acc = 0.f;
    #pragma unroll
    for (int k = 0; k < 16; k++) acc += Ss[pi * 8 + k] * Es[k * 256 + tid];
    float ang = (float)p * dv;
    float pe = (tid & 1) ? cosf(ang) : sinf(ang);
    float ov = acc + pe;
    dst[((size_t)bn * np + p) * D_ + tid] = f2bf(ov);
    if (mode == 1) {
      float s = ov, q = ov * ov;
      #pragma unroll
      for (int off = 32; off > 0; off >>= 1) { s += __shfl_xor(s, off); q += __shfl_xor(q, off); }
      if (l == 0) { pS[pi][w] = s; pQ[pi][w] = q; }
    }
  }
  if (mode == 1) {
    __syncthreads();
    if (tid < 15) {
      float S = pS[tid][0] + pS[tid][1] + pS[tid][2] + pS[tid][3];
      float Q = pQ[tid][0] + pQ[tid][1] + pQ[tid][2] + pQ[tid][3];
      float mu = S * (1.f / 256.f);
      int idx = bn * 90 + p0 + tid;
      muX[idx] = mu;
      rsX[idx] = rsqrtf(Q * (1.f / 256.f) - mu * mu + EPS_);
    }
  }
}

// ---------------- K_conv: ALL weights, single launch, double-buffered pipeline ----------------
// tile ranges: [0,17280) temp 6x180x16 (256x256 -> 256x256)
//              [17280,31104) chan 6x256x9 (180x180 -> 192x192 padded)
//              [31104,39744) head 720x12 (46080x720 -> 46080x768 padded)
struct TileInfo {
  const float* Wg; unsigned short* Og;
  int K, Nn, Kp, k0, n0;
};

__device__ __forceinline__ TileInfo decode_tile(
    int bid,
    const float* t0, const float* t1, const float* t2, const float* t3,
    const float* t4, const float* t5,
    const float* c0, const float* c1, const float* c2, const float* c3,
    const float* c4p, const float* c5, const float* hw,
    unsigned short* WtAll, unsigned short* WcAll, unsigned short* WhAll) {
  TileInfo ti;
  int tk, tn;
  if (bid < 17280) {
    int tt = bid / 2880, rem = bid - tt * 2880;
    int g = rem >> 4, tile = rem & 15;
    const float* s = t0;
    if (tt == 1) s = t1; else if (tt == 2) s = t2; else if (tt == 3) s = t3;
    else if (tt == 4) s = t4; else if (tt == 5) s = t5;
    ti.Wg = s + (size_t)g * 65536;
    ti.Og = WtAll + (size_t)tt * 11796480 + (size_t)g * 65536;
    ti.K = 256; ti.Nn = 256; ti.Kp = 256; tk = tile >> 2; tn = tile & 3;
  } else if (bid < 31104) {
    int b2 = bid - 17280;
    int tt = b2 / 2304, rem = b2 - tt * 2304;
    int g = rem / 9, tile = rem - g * 9;
    const float* s = c0;
    if (tt == 1) s = c1; else if (tt == 2) s = c2; else if (tt == 3) s = c3;
    else if (tt == 4) s = c4p; else if (tt == 5) s = c5;
    ti.Wg = s + (size_t)g * 32400;
    ti.Og = WcAll + (size_t)tt * 9437184 + (size_t)g * 36864;
    ti.K = 180; ti.Nn = 180; ti.Kp = 192; tk = tile / 3; tn = tile - (tile / 3) * 3;
  } else {
    int b2 = bid - 31104;
    ti.Wg = hw; ti.Og = WhAll;
    ti.K = 46080; ti.Nn = 720; ti.Kp = 46080; tk = b2 / 12; tn = b2 - (b2 / 12) * 12;
  }
  ti.k0 = tk * 64; ti.n0 = tn * 64;
  return ti;
}

__global__ __launch_bounds__(256) void convT_all_kernel(
    const float* t0, const float* t1, const float* t2, const float* t3,
    const float* t4, const float* t5,
    const float* c0, const float* c1, const float* c2, const float* c3,
    const float* c4p, const float* c5,
    const float* hw,
    unsigned short* WtAll, unsigned short* WcAll, unsigned short* WhAll,
    int phase, int step) {
  __shared__ float Ts[2][64][65];
  int tid = threadIdx.x;
  int kr = tid >> 4, nc = (tid & 15) * 4;
  int S = gridDim.x * step;

  auto do_load = [&](const TileInfo& ti, float4* r) {
    #pragma unroll
    for (int i = 0; i < 4; i++) {
      int k = ti.k0 + kr + i * 16;
      float4 v = make_float4(0.f, 0.f, 0.f, 0.f);
      if (k < ti.K) {
        int n = ti.n0 + nc;
        if (n + 3 < ti.Nn) {
          v = *reinterpret_cast<const float4*>(ti.Wg + (size_t)k * ti.Nn + n);
        } else {
          if (n + 0 < ti.Nn) v.x = ti.Wg[(size_t)k * ti.Nn + n + 0];
          if (n + 1 < ti.Nn) v.y = ti.Wg[(size_t)k * ti.Nn + n + 1];
          if (n + 2 < ti.Nn) v.z = ti.Wg[(size_t)k * ti.Nn + n + 2];
          if (n + 3 < ti.Nn) v.w = ti.Wg[(size_t)k * ti.Nn + n + 3];
        }
      }
      r[i] = v;
    }
  };

  auto do_write = [&](const float4* r, int b) {
    #pragma unroll
    for (int i = 0; i < 4; i++) {
      Ts[b][kr + i * 16][nc + 0] = r[i].x;
      Ts[b][kr + i * 16][nc + 1] = r[i].y;
      Ts[b][kr + i * 16][nc + 2] = r[i].z;
      Ts[b][kr + i * 16][nc + 3] = r[i].w;
    }
  };

  auto do_store = [&](const TileInfo& ti, int b) {
    #pragma unroll
    for (int it = 0; it < 2; it++) {
      int nr = (tid >> 3) + it * 32;
      int kc = (tid & 7) * 8;
      unsigned int tmp[4];
      #pragma unroll
      for (int j = 0; j < 4; j++) {
        unsigned int lo = f2bf(Ts[b][kc + 2 * j][nr]);
        unsigned int hi = f2bf(Ts[b][kc + 2 * j + 1][nr]);
        tmp[j] = lo | (hi << 16);
      }
      uint4 vv; vv.x = tmp[0]; vv.y = tmp[1]; vv.z = tmp[2]; vv.w = tmp[3];
      *reinterpret_cast<uint4*>(ti.Og + (size_t)(ti.n0 + nr) * ti.Kp + ti.k0 + kc) = vv;
    }
  };

#define DECODE(tt) decode_tile((tt), t0,t1,t2,t3,t4,t5, c0,c1,c2,c3,c4p,c5, hw, WtAll, WcAll, WhAll)

  int t = phase + blockIdx.x * step;
  if (t >= NTILE_) return;

  float4 rA[4], rB[4];
  TileInfo i0 = DECODE(t);
  do_load(i0, rA);
  bool v1 = (t + S < NTILE_);
  TileInfo i1 = v1 ? DECODE(t + S) : i0;
  if (v1) do_load(i1, rB);
  do_write(rA, 0);                         // waits rA (tile t)
  bool v2 = (t + 2 * S < NTILE_);
  TileInfo i2 = v2 ? DECODE(t + 2 * S) : i0;
  if (v2) do_load(i2, rA);                 // reuse rA slot for t+2S
  __syncthreads();

  // Invariant at top of phase A: Ts[0]=tile t (ready); rB=t+S; rA=t+2S (flight)
  while (true) {
    // ---- phase A: tile t from buf 0 ----
    if (v1) do_write(rB, 1);               // waits rB only (oldest loads)
    {
      bool v3 = (t + 3 * S < NTILE_);
      TileInfo i3 = i2;
      if (v3) { i3 = DECODE(t + 3 * S); do_load(i3, rB); }
      do_store(i0, 0);
      __syncthreads();
      t += S;
      if (!v1) return;
      i0 = i1; i1 = i2; i2 = i3; v1 = v2; v2 = v3;
    }
    // ---- phase B: tile t from buf 1 (regs swapped) ----
    if (v1) do_write(rA, 0);
    {
      bool v3 = (t + 3 * S < NTILE_);
      TileInfo i3 = i2;
      if (v3) { i3 = DECODE(t + 3 * S); do_load(i3, rA); }
      do_store(i0, 1);
      __syncthreads();
      t += S;
      if (!v1) return;
      i0 = i1; i1 = i2; i2 = i3; v1 = v2; v2 = v3;
    }
  }
#undef DECODE
}

// ---------------- K4: temp mix MFMA, single-LDS-buffer, coalesced X restage for residual ----------------
// Round-5 fixes vs round 4: __launch_bounds__(256,3) (bounds-4 capped VGPR at 64
// -> acc spilled to scratch: WRITE_SIZE 119MB vs 23.6 ideal). Residual now comes
// from a COALESCED restage of X into Xs after GEMM2 (round 4's per-lane 2-byte
// global reads overfetched ~2x and missed L2). Same bf16 bits either way.
__global__ __launch_bounds__(256, 3) void temp_mfma_kernel(
    const unsigned short* __restrict__ X, unsigned short* __restrict__ Y,
    const unsigned short* __restrict__ W1t, const float* __restrict__ B1,
    const unsigned short* __restrict__ W2t, const float* __restrict__ B2,
    const float* __restrict__ NW, const float* __restrict__ NB) {
  __shared__ __align__(16) short Xs[64 * 256];
  __shared__ float partS[64][4];
  __shared__ float partQ[64][4];
  int lin = (blockIdx.x & 7) * 90 + (blockIdx.x >> 3);  // bijective, 720 % 8 == 0
  int p = lin >> 2;
  int m0 = (lin & 3) << 6;
  int tid = threadIdx.x;
  int w = tid >> 6, l = tid & 63;
  int lr = l & 15, lq = l >> 4;
  int n0w = w << 6;

  const unsigned short* W1p = W1t + (size_t)p * 65536;
  const unsigned short* W2p = W2t + (size_t)p * 65536;

  // issue first W1 fragments early — latency hides under X staging + barrier
  bf16x8 bhc[4], bhn[4];
  #pragma unroll
  for (int nf = 0; nf < 4; nf++)
    bhc[nf] = *reinterpret_cast<const bf16x8*>(W1p + (size_t)(n0w + nf * 16 + lr) * 256 + lq * 8);

  const unsigned short* Xblk = X + (size_t)m0 * PD_ + (size_t)p * D_;
  for (int i = tid; i < 64 * 32; i += 256) {
    int r = i >> 5, c8 = (i & 31) << 3;
    uint4 v = *reinterpret_cast<const uint4*>(Xblk + (size_t)r * PD_ + c8);
    *reinterpret_cast<uint4*>(&Xs[r * 256 + (c8 ^ ((r & 7) << 3))]) = v;
  }
  __syncthreads();

  f32x4 zero4 = {0.f, 0.f, 0.f, 0.f};
  f32x4 acc[4][4];
  #pragma unroll
  for (int a = 0; a < 4; a++)
    #pragma unroll
    for (int b = 0; b < 4; b++) acc[a][b] = zero4;

  for (int ks = 0; ks < 8; ks++) {
    int kb = ks * 32 + lq * 8;
    bf16x8 af[4];
    #pragma unroll
    for (int mf = 0; mf < 4; mf++) {
      int r = mf * 16 + lr;
      af[mf] = *reinterpret_cast<const bf16x8*>(&Xs[r * 256 + (kb ^ ((r & 7) << 3))]);
    }
    if (ks < 7) {
      #pragma unroll
      for (int nf = 0; nf < 4; nf++)
        bhn[nf] = *reinterpret_cast<const bf16x8*>(W1p + (size_t)(n0w + nf * 16 + lr) * 256 + kb + 32);
    }
    #pragma unroll
    for (int mf = 0; mf < 4; mf++)
      #pragma unroll
      for (int nf = 0; nf < 4; nf++)
        acc[mf][nf] = __builtin_amdgcn_mfma_f32_16x16x32_bf16(af[mf], bhc[nf], acc[mf][nf], 0, 0, 0);
    if (ks < 7) {
      #pragma unroll
      for (int nf = 0; nf < 4; nf++) bhc[nf] = bhn[nf];
    }
  }

  // issue first W2 fragments now — latency hides under GELU VALU phase
  bf16x8 bh2[4];
  #pragma unroll
  for (int nf = 0; nf < 4; nf++)
    bh2[nf] = *reinterpret_cast<const bf16x8*>(W2p + (size_t)(n0w + nf * 16 + lr) * 256 + lq * 8);

  __syncthreads();   // all waves done reading X from Xs

  // bias + gelu -> overwrite Xs (bf16, swizzled; same pattern GEMM2 expects)
  #pragma unroll
  for (int nf = 0; nf < 4; nf++) {
    int n = n0w + nf * 16 + lr;
    float bias = B1[p * 256 + n];
    #pragma unroll
    for (int mf = 0; mf < 4; mf++)
      #pragma unroll
      for (int rg = 0; rg < 4; rg++) {
        int r = mf * 16 + lq * 4 + rg;
        Xs[r * 256 + (n ^ ((r & 7) << 3))] =
            (short)f2bf(gelu_exact(acc[mf][nf][rg] + bias));
      }
  }
  __syncthreads();

  #pragma unroll
  for (int a = 0; a < 4; a++)
    #pragma unroll
    for (int b = 0; b < 4; b++) acc[a][b] = zero4;
  for (int ks = 0; ks < 8; ks++) {
    int kb = ks * 32 + lq * 8;
    bf16x8 af[4];
    #pragma unroll
    for (int mf = 0; mf < 4; mf++) {
      int r = mf * 16 + lr;
      af[mf] = *reinterpret_cast<const bf16x8*>(&Xs[r * 256 + (kb ^ ((r & 7) << 3))]);
    }
    if (ks < 7) {
      #pragma unroll
      for (int nf = 0; nf < 4; nf++)
        bhn[nf] = *reinterpret_cast<const bf16x8*>(W2p + (size_t)(n0w + nf * 16 + lr) * 256 + kb + 32);
    }
    #pragma unroll
    for (int mf = 0; mf < 4; mf++)
      #pragma unroll
      for (int nf = 0; nf < 4; nf++)
        acc[mf][nf] = __builtin_amdgcn_mfma_f32_16x16x32_bf16(af[mf], bh2[nf], acc[mf][nf], 0, 0, 0);
    if (ks < 7) {
      #pragma unroll
      for (int nf = 0; nf < 4; nf++) bh2[nf] = bhn[nf];
    }
  }

  __syncthreads();   // all waves done reading H from Xs

  // coalesced restage of X into Xs (same swizzle as entry) for residual reads
  for (int i = tid; i < 64 * 32; i += 256) {
    int r = i >> 5, c8 = (i & 31) << 3;
    uint4 v = *reinterpret_cast<const uint4*>(Xblk + (size_t)r * PD_ + c8);
    *reinterpret_cast<uint4*>(&Xs[r * 256 + (c8 ^ ((r & 7) << 3))]) = v;
  }
  __syncthreads();

  // epilogue: o = acc + b2 + residual (from LDS, exact bf16 bits), fused LN
  float b2v[4], nwv[4], nbv[4];
  #pragma unroll
  for (int nf = 0; nf < 4; nf++) {
    int n = n0w + nf * 16 + lr;
    b2v[nf] = B2[p * 256 + n];
    nwv[nf] = NW[n];
    nbv[nf] = NB[n];
  }
  #pragma unroll
  for (int nf = 0; nf < 4; nf++) {
    int n = n0w + nf * 16 + lr;
    #pragma unroll
    for (int mf = 0; mf < 4; mf++)
      #pragma unroll
      for (int rg = 0; rg < 4; rg++) {
        int r = mf * 16 + lq * 4 + rg;
        float res = bf2f((unsigned short)Xs[r * 256 + (n ^ ((r & 7) << 3))]);
        acc[mf][nf][rg] += b2v[nf] + res;
      }
  }
  #pragma unroll
  for (int mf = 0; mf < 4; mf++)
    #pragma unroll
    for (int rg = 0; rg < 4; rg++) {
      float s = acc[mf][0][rg] + acc[mf][1][rg] + acc[mf][2][rg] + acc[mf][3][rg];
      float q = acc[mf][0][rg] * acc[mf][0][rg] + acc[mf][1][rg] * acc[mf][1][rg] +
                acc[mf][2][rg] * acc[mf][2][rg] + acc[mf][3][rg] * acc[mf][3][rg];
      #pragma unroll
      for (int off = 1; off < 16; off <<= 1) {
        s += __shfl_xor(s, off);
        q += __shfl_xor(q, off);
      }
      if (lr == 0) {
        int r = mf * 16 + lq * 4 + rg;
        partS[r][w] = s;
        partQ[r][w] = q;
      }
    }
  __syncthreads();   // partS/partQ ready; residual reads of Xs done
  #pragma unroll
  for (int mf = 0; mf < 4; mf++)
    #pragma unroll
    for (int rg = 0; rg < 4; rg++) {
      int r = mf * 16 + lq * 4 + rg;
      float S = partS[r][0] + partS[r][1] + partS[r][2] + partS[r][3];
      float Q = partQ[r][0] + partQ[r][1] + partQ[r][2] + partQ[r][3];
      float mu = S * (1.f / 256.f);
      float rstd = rsqrtf(Q * (1.f / 256.f) - mu * mu + EPS_);
      #pragma unroll
      for (int nf = 0; nf < 4; nf++) {
        int n = n0w + nf * 16 + lr;
        Xs[r * 256 + (n ^ ((r & 7) << 3))] =
            (short)f2bf((acc[mf][nf][rg] - mu) * rstd * nwv[nf] + nbv[nf]);
      }
    }
  __syncthreads();
  unsigned short* Yblk = Y + (size_t)m0 * PD_ + (size_t)p * D_;
  for (int i = tid; i < 64 * 32; i += 256) {
    int r = i >> 5, c8 = (i & 31) << 3;
    uint4 v = *reinterpret_cast<uint4*>(&Xs[r * 256 + (c8 ^ ((r & 7) << 3))]);
    *reinterpret_cast<uint4*>(Yblk + (size_t)r * PD_ + c8) = v;
  }
}

// ---------------- K_trAB: A bf16 [bn*180+p][256] -> B bf16 [bn*256+d][192] ----------------
__global__ __launch_bounds__(256) void tr_AB_kernel(
    const unsigned short* __restrict__ A, unsigned short* __restrict__ B16) {
  __shared__ unsigned short T[32][184];
  int bn = blockIdx.y;
  int d0 = blockIdx.x * 32;
  int tid = threadIdx.x;
  int ld = tid & 31, pw = tid >> 5;
  for (int p = pw; p < 180; p += 8)
    T[ld][p] = A[((size_t)bn * 180 + p) * 256 + d0 + ld];
  __syncthreads();
  unsigned int* Bu = reinterpret_cast<unsigned int*>(B16);
  for (int i = tid; i < 32 * 96; i += 256) {
    int r = i / 96, jj = i - r * 96;
    int p0 = 2 * jj;
    unsigned int lo = (p0 < 180) ? (unsigned int)T[r][p0] : 0u;
    unsigned int hi = (p0 + 1 < 180) ? (unsigned int)T[r][p0 + 1] : 0u;
    Bu[((size_t)bn * 256 + d0 + r) * 96 + jj] = lo | (hi << 16);
  }
}

// ---------------- K5: chan mix MFMA, single-LDS-buffer, coalesced Xb restage for residual ----------------
__global__ __launch_bounds__(256, 3) void chan_mfma_kernel(
    const unsigned short* __restrict__ Xb, unsigned short* __restrict__ Yb,
    const unsigned short* __restrict__ W1t, const float* __restrict__ B1,
    const unsigned short* __restrict__ W2t, const float* __restrict__ B2) {
  __shared__ __align__(16) short Xs[64 * 200];
  int lin = (blockIdx.x & 7) * 128 + (blockIdx.x >> 3);  // 1024 % 8 == 0
  int d = lin >> 2;
  int m0 = (lin & 3) << 6;
  int tid = threadIdx.x;
  int w = tid >> 6, l = tid & 63;
  int lr = l & 15, lq = l >> 4;
  int n0w = w * 48;

  const unsigned short* W1p = W1t + (size_t)d * (192 * 192);
  const unsigned short* W2p = W2t + (size_t)d * (192 * 192);

  // issue first W1 fragments early — latency hides under X staging + barrier
  bf16x8 bhc[3], bhn[3];
  #pragma unroll
  for (int nf = 0; nf < 3; nf++)
    bhc[nf] = *reinterpret_cast<const bf16x8*>(W1p + (size_t)(n0w + nf * 16 + lr) * 192 + lq * 8);

  for (int i = tid; i < 64 * 24; i += 256) {
    int r = i / 24, c = i - r * 24;
    uint4 v = *reinterpret_cast<const uint4*>(
        Xb + ((size_t)(m0 + r) * 256 + d) * 192 + c * 8);
    *reinterpret_cast<uint4*>(&Xs[r * 200 + c * 8]) = v;
  }
  __syncthreads();

  f32x4 zero4 = {0.f, 0.f, 0.f, 0.f};
  f32x4 acc[4][3];
  #pragma unroll
  for (int a = 0; a < 4; a++)
    #pragma unroll
    for (int b = 0; b < 3; b++) acc[a][b] = zero4;

  for (int ks = 0; ks < 6; ks++) {
    int kb = ks * 32 + lq * 8;
    bf16x8 af[4];
    #pragma unroll
    for (int mf = 0; mf < 4; mf++)
      af[mf] = *reinterpret_cast<const bf16x8*>(&Xs[(mf * 16 + lr) * 200 + kb]);
    if (ks < 5) {
      #pragma unroll
      for (int nf = 0; nf < 3; nf++)
        bhn[nf] = *reinterpret_cast<const bf16x8*>(W1p + (size_t)(n0w + nf * 16 + lr) * 192 + kb + 32);
    }
    #pragma unroll
    for (int mf = 0; mf < 4; mf++)
      #pragma unroll
      for (int nf = 0; nf < 3; nf++)
        acc[mf][nf] = __builtin_amdgcn_mfma_f32_16x16x32_bf16(af[mf], bhc[nf], acc[mf][nf], 0, 0, 0);
    if (ks < 5) {
      #pragma unroll
      for (int nf = 0; nf < 3; nf++) bhc[nf] = bhn[nf];
    }
  }

  // issue first W2 fragments now — latency hides under GELU VALU phase
  bf16x8 bh2[3];
  #pragma unroll
  for (int nf = 0; nf < 3; nf++)
    bh2[nf] = *reinterpret_cast<const bf16x8*>(W2p + (size_t)(n0w + nf * 16 + lr) * 192 + lq * 8);

  __syncthreads();   // all waves done reading X from Xs

  #pragma unroll
  for (int nf = 0; nf < 3; nf++) {
    int n = n0w + nf * 16 + lr;
    bool valid = n < 180;
    float bias = valid ? B1[d * 180 + n] : 0.f;
    #pragma unroll
    for (int mf = 0; mf < 4; mf++)
      #pragma unroll
      for (int rg = 0; rg < 4; rg++) {
        int r = mf * 16 + lq * 4 + rg;
        float h = valid ? gelu_exact(acc[mf][nf][rg] + bias) : 0.f;
        Xs[r * 200 + n] = (short)f2bf(h);
      }
  }
  __syncthreads();

  #pragma unroll
  for (int a = 0; a < 4; a++)
    #pragma unroll
    for (int b = 0; b < 3; b++) acc[a][b] = zero4;
  for (int ks = 0; ks < 6; ks++) {
    int kb = ks * 32 + lq * 8;
    bf16x8 af[4];
    #pragma unroll
    for (int mf = 0; mf < 4; mf++)
      af[mf] = *reinterpret_cast<const bf16x8*>(&Xs[(mf * 16 + lr) * 200 + kb]);
    if (ks < 5) {
      #pragma unroll
      for (int nf = 0; nf < 3; nf++)
        bhn[nf] = *reinterpret_cast<const bf16x8*>(W2p + (size_t)(n0w + nf * 16 + lr) * 192 + kb + 32);
    }
    #pragma unroll
    for (int mf = 0; mf < 4; mf++)
      #pragma unroll
      for (int nf = 0; nf < 3; nf++)
        acc[mf][nf] = __builtin_amdgcn_mfma_f32_16x16x32_bf16(af[mf], bh2[nf], acc[mf][nf], 0, 0, 0);
    if (ks < 5) {
      #pragma unroll
      for (int nf = 0; nf < 3; nf++) bh2[nf] = bhn[nf];
    }
  }

  __syncthreads();   // all waves done reading H from Xs

  // coalesced restage of Xb into Xs (same layout as entry) for residual reads
  for (int i = tid; i < 64 * 24; i += 256) {
    int r = i / 24, c = i - r * 24;
    uint4 v = *reinterpret_cast<const uint4*>(
        Xb + ((size_t)(m0 + r) * 256 + d) * 192 + c * 8);
    *reinterpret_cast<uint4*>(&Xs[r * 200 + c * 8]) = v;
  }
  __syncthreads();

  #pragma unroll
  for (int nf = 0; nf < 3; nf++) {
    int n = n0w + nf * 16 + lr;
    if (n < 180) {
      float b2v = B2[d * 180 + n];
      #pragma unroll
      for (int mf = 0; mf < 4; mf++)
        #pragma unroll
        for (int rg = 0; rg < 4; rg++) {
          int r = mf * 16 + lq * 4 + rg;
          float res = bf2f((unsigned short)Xs[r * 200 + n]);
          Yb[((size_t)(m0 + r) * 256 + d) * 180 + n] = f2bf(acc[mf][nf][rg] + b2v + res);
        }
    }
  }
}

// ---------------- K_trLN: Yb bf16 -> A bf16 with LN over d, comb fuse, P-stats fold ----------------
__global__ __launch_bounds__(256) void trLN_kernel(
    const unsigned short* __restrict__ Bsrc, unsigned short* __restrict__ A,
    const float* __restrict__ nw, const float* __restrict__ nb,
    const float* __restrict__ cw, const float* __restrict__ cb, int useComb,
    float* __restrict__ muP, float* __restrict__ rsP) {
  __shared__ float Tl[16][260];
  int bn = blockIdx.y;
  int p0 = blockIdx.x * 16;
  int tid = threadIdx.x;
  int j = tid & 15, db = tid >> 4;
  #pragma unroll 4
  for (int it = 0; it < 16; ++it) {
    int dd = it * 16 + db;
    float v = 0.f;
    if (p0 + j < 180)
      v = bf2f(Bsrc[((size_t)(bn * 256) + dd) * 180 + p0 + j]);
    Tl[j][dd] = v;
  }
  __syncthreads();
  int w = tid >> 6, l = tid & 63;
  float scale = 1.f, shift = 0.f;
  if (useComb) { scale = cw[0]; shift = cb[0]; }
  float4 w4 = *reinterpret_cast<const float4*>(nw + l * 4);
  float4 b4 = *reinterpret_cast<const float4*>(nb + l * 4);
  #pragma unroll
  for (int rr = 0; rr < 4; ++rr) {
    int row = w * 4 + rr;
    int p = p0 + row;
    float4 v = *reinterpret_cast<const float4*>(&Tl[row][l * 4]);
    float s = v.x + v.y + v.z + v.w;
    float s2 = v.x*v.x + v.y*v.y + v.z*v.z + v.w*v.w;
    #pragma unroll
    for (int off = 32; off > 0; off >>= 1) { s += __shfl_xor(s, off); s2 += __shfl_xor(s2, off); }
    float mu = s * (1.f/256.f);
    float rstd = rsqrtf(s2 * (1.f/256.f) - mu * mu + EPS_);
    if (p < 180) {
      float o0 = ((v.x - mu) * rstd * w4.x + b4.x) * scale + shift;
      float o1 = ((v.y - mu) * rstd * w4.y + b4.y) * scale + shift;
      float o2 = ((v.z - mu) * rstd * w4.z + b4.z) * scale + shift;
      float o3 = ((v.w - mu) * rstd * w4.w + b4.w) * scale + shift;
      unsigned int w0 = (unsigned int)f2bf(o0) | ((unsigned int)f2bf(o1) << 16);
      unsigned int w1 = (unsigned int)f2bf(o2) | ((unsigned int)f2bf(o3) << 16);
      unsigned int* dst = reinterpret_cast<unsigned int*>(
          A + ((size_t)bn * 180 + p) * 256 + l * 4);
      dst[0] = w0; dst[1] = w1;
      if (useComb && p < 90) {
        float so = o0 + o1 + o2 + o3;
        float qo = o0*o0 + o1*o1 + o2*o2 + o3*o3;
        #pragma unroll
        for (int off = 32; off > 0; off >>= 1) { so += __shfl_xor(so, off); qo += __shfl_xor(qo, off); }
        if (l == 0) {
          float muo = so * (1.f/256.f);
          muP[bn * 90 + p] = muo;
          rsP[bn * 90 + p] = rsqrtf(qo * (1.f/256.f) - muo * muo + EPS_);
        }
      }
    }
  }
}

// ---------------- K8: circular autocorrelation, 2-wave lag split, unroll-4 rotation ----------------
__global__ __launch_bounds__(128, 1) void autocorr_kernel(
    const unsigned short* __restrict__ xoldB, const unsigned short* __restrict__ xcB,
    const float* __restrict__ muX, const float* __restrict__ rsX,
    const float* __restrict__ muP, const float* __restrict__ rsP,
    const float* __restrict__ lnw, const float* __restrict__ lnb,
    float* __restrict__ sqa) {
  __shared__ float PI[46][64];
  __shared__ float RED[2][2][64];
  int bn = blockIdx.x >> 2;
  int tid = threadIdx.x;
  int dl = tid & 63;
  int half = tid >> 6;
  int j0 = half * 23;
  int d = ((blockIdx.x & 3) << 6) + dl;
  float w = lnw[d], bb = lnb[d];
  float v[90], wr[90];

  {
    const unsigned short* col = xcB + (size_t)bn * PD_ + d;
    const float* m = muP + bn * 90;
    const float* rs = rsP + bn * 90;
    #pragma unroll
    for (int p = 0; p < 90; p++)
      v[p] = (bf2f(col[(size_t)p * D_]) - m[p]) * rs[p] * w + bb;
    #pragma unroll
    for (int p = 0; p < 90; p++)
      wr[p] = (half == 0) ? v[p] : v[(p + 23) % 90];
  }
  float den = 0.f;
  #pragma unroll 1
  for (int jt = 0; jt < 24; jt += 4) {
    float c0 = 0.f, c1 = 0.f, c2 = 0.f, c3 = 0.f;
    #pragma unroll
    for (int mm = 0; mm < 90; mm++) {
      float vm = v[mm];
      c0 += vm * wr[mm];
      c1 += vm * ((mm + 1 < 90) ? wr[mm + 1] : wr[mm - 89]);
      c2 += vm * ((mm + 2 < 90) ? wr[mm + 2] : wr[mm - 88]);
      c3 += vm * ((mm + 3 < 90) ? wr[mm + 3] : wr[mm - 87]);
    }
    float cq[4] = {c0, c1, c2, c3};
    #pragma unroll
    for (int q = 0; q < 4; q++) {
      if (jt + q < 23) {
        int lag = j0 + jt + q;
        float piv = fmaxf(cq[q] * 0.10540925533894598f, 0.f);
        PI[lag][dl] = piv;
        float wgt = (lag == 0 || lag == 45) ? 1.f : 2.f;
        den += wgt * piv * piv;
      }
    }
    float t0 = wr[0], t1 = wr[1], t2 = wr[2], t3 = wr[3];
    #pragma unroll
    for (int mm = 0; mm < 86; mm++) wr[mm] = wr[mm + 4];
    wr[86] = t0; wr[87] = t1; wr[88] = t2; wr[89] = t3;
  }

  {
    const unsigned short* col = xoldB + (size_t)bn * (PO_ * D_) + d;
    const float* m = muX + bn * 90;
    const float* rs = rsX + bn * 90;
    #pragma unroll
    for (int p = 0; p < 90; p++)
      v[p] = (bf2f(col[(size_t)p * D_]) - m[p]) * rs[p] * w + bb;
    #pragma unroll
    for (int p = 0; p < 90; p++)
      wr[p] = (half == 0) ? v[p] : v[(p + 23) % 90];
  }
  float num = 0.f;
  #pragma unroll 1
  for (int jt = 0; jt < 24; jt += 4) {
    float c0 = 0.f, c1 = 0.f, c2 = 0.f, c3 = 0.f;
    #pragma unroll
    for (int mm = 0; mm < 90; mm++) {
      float vm = v[mm];
      c0 += vm * wr[mm];
      c1 += vm * ((mm + 1 < 90) ? wr[mm + 1] : wr[mm - 89]);
      c2 += vm * ((mm + 2 < 90) ? wr[mm + 2] : wr[mm - 88]);
      c3 += vm * ((mm + 3 < 90) ? wr[mm + 3] : wr[mm - 87]);
    }
    float cq[4] = {c0, c1, c2, c3};
    #pragma unroll
    for (int q = 0; q < 4; q++) {
      if (jt + q < 23) {
        int lag = j0 + jt + q;
        float xi = fmaxf(cq[q] * 0.10540925533894598f, 0.f);
        float wgt = (lag == 0 || lag == 45) ? 1.f : 2.f;
        num += wgt * xi * PI[lag][dl];
      }
    }
    float t0 = wr[0], t1 = wr[1], t2 = wr[2], t3 = wr[3];
    #pragma unroll
    for (int mm = 0; mm < 86; mm++) wr[mm] = wr[mm + 4];
    wr[86] = t0; wr[87] = t1; wr[88] = t2; wr[89] = t3;
  }
  RED[0][half][dl] = den;
  RED[1][half][dl] = num;
  __syncthreads();
  if (half == 0) {
    float Dn = RED[0][0][dl] + RED[0][1][dl];
    float Nm = RED[1][0][dl] + RED[1][1][dl];
    sqa[bn * D_ + d] = sqrtf(Nm / (Dn + 0.001f));
  }
}

// ---------------- K9: scale by sqrt(alpha), transpose to [bn][d][p], bf16 in/out ----------------
__global__ __launch_bounds__(256) void scale_tr_kernel(
    const unsigned short* __restrict__ Xc, const float* __restrict__ sqa,
    unsigned short* __restrict__ Xt) {
  __shared__ float Ts[32][33];
  int bn = blockIdx.y;
  int pt = blockIdx.x % 6, dt = blockIdx.x / 6;
  int p0 = pt * 32, d0 = dt * 32;
  int tid = threadIdx.x;
  {
    int pr = tid >> 3, c4 = (tid & 7) * 4;
    if (p0 + pr < 180) {
      u16x4 h = *reinterpret_cast<const u16x4*>(
          Xc + ((size_t)bn * 180 + p0 + pr) * 256 + d0 + c4);
      Ts[pr][c4]   = bf2f(h[0]); Ts[pr][c4+1] = bf2f(h[1]);
      Ts[pr][c4+2] = bf2f(h[2]); Ts[pr][c4+3] = bf2f(h[3]);
    }
  }
  __syncthreads();
  {
    int dr = tid >> 3, p4 = (tid & 7) * 4;
    float sc = sqa[bn * D_ + d0 + dr];
    #pragma unroll
    for (int i = 0; i < 4; i++) {
      int pp = p0 + p4 + i;
      if (pp < 180)
        Xt[(size_t)bn * PD_ + (size_t)(d0 + dr) * 180 + pp] = f2bf(Ts[p4 + i][dr] * sc);
    }
  }
}

// ---------------- K10: head GEMM MFMA, K-split 16, A/B prefetch ----------------
__global__ __launch_bounds__(256, 2) void head_mfma_kernel(
    const unsigned short* __restrict__ A, const unsigned short* __restrict__ Bw,
    float* __restrict__ P) {
  __shared__ float Rs[64][65];
  int lin = (blockIdx.x & 7) * 96 + (blockIdx.x >> 3);  // 768 % 8 == 0
  int ks = lin / 48;
  int rem = lin - ks * 48;
  int mt = rem & 3, nt = rem >> 2;
  int m0 = mt << 6, n0 = nt << 6;
  int tid = threadIdx.x;
  int w = tid >> 6, l = tid & 63;
  int lr = l & 15, lq = l >> 4;
  f32x4 zero4 = {0.f, 0.f, 0.f, 0.f};
  f32x4 acc[4][4];
  #pragma unroll
  for (int a = 0; a < 4; a++)
    #pragma unroll
    for (int b = 0; b < 4; b++) acc[a][b] = zero4;

  size_t kbase = (size_t)ks * 2880;
  bf16x8 afc[4], bhc[4], afn[4], bhn[4];
  {
    size_t kb = kbase + (size_t)w * 32 + lq * 8;
    #pragma unroll
    for (int mf = 0; mf < 4; mf++)
      afc[mf] = *reinterpret_cast<const bf16x8*>(A + (size_t)(m0 + mf * 16 + lr) * 46080 + kb);
    #pragma unroll
    for (int nf = 0; nf < 4; nf++)
      bhc[nf] = *reinterpret_cast<const bf16x8*>(Bw + (size_t)(n0 + nf * 16 + lr) * 46080 + kb);
  }
  for (int s = w; s < 90; s += 4) {
    int sn = s + 4;
    if (sn < 90) {
      size_t kb = kbase + (size_t)sn * 32 + lq * 8;
      #pragma unroll
      for (int mf = 0; mf < 4; mf++)
        afn[mf] = *reinterpret_cast<const bf16x8*>(A + (size_t)(m0 + mf * 16 + lr) * 46080 + kb);
      #pragma unroll
      for (int nf = 0; nf < 4; nf++)
        bhn[nf] = *reinterpret_cast<const bf16x8*>(Bw + (size_t)(n0 + nf * 16 + lr) * 46080 + kb);
    }
    #pragma unroll
    for (int mf = 0; mf < 4; mf++)
      #pragma unroll
      for (int nf = 0; nf < 4; nf++)
        acc[mf][nf] = __builtin_amdgcn_mfma_f32_16x16x32_bf16(afc[mf], bhc[nf], acc[mf][nf], 0, 0, 0);
    if (sn < 90) {
      #pragma unroll
      for (int mf = 0; mf < 4; mf++) afc[mf] = afn[mf];
      #pragma unroll
      for (int nf = 0; nf < 4; nf++) bhc[nf] = bhn[nf];
    }
  }
  for (int ww = 0; ww < 4; ww++) {
    if (w == ww) {
      #pragma unroll
      for (int mf = 0; mf < 4; mf++)
        #pragma unroll
        for (int nf = 0; nf < 4; nf++)
          #pragma unroll
          for (int rg = 0; rg < 4; rg++) {
            int r = mf * 16 + lq * 4 + rg, c = nf * 16 + lr;
            if (ww == 0) Rs[r][c] = acc[mf][nf][rg];
            else Rs[r][c] += acc[mf][nf][rg];
          }
    }
    __syncthreads();
  }
  for (int i = tid; i < 64 * 64; i += 256) {
    int r = i >> 6, c = i & 63;
    int n = n0 + c;
    if (n < 720)
      P[((size_t)ks * 256 + m0 + r) * 720 + n] = Rs[r][c];
  }
}

// ---------------- K11: reduce partials + final revin inverse + transpose out ----------------
__global__ __launch_bounds__(256) void final_kernel(
    const float* __restrict__ P, const float* __restrict__ hb,
    const float* __restrict__ rw, const float* __restrict__ rb,
    const float* __restrict__ meanA, const float* __restrict__ stdevA,
    float* __restrict__ out) {
  int gid = blockIdx.x * 256 + threadIdx.x;  // < 184320
  int bn = gid / 720, t = gid - bn * 720;
  float s = 0.f;
  #pragma unroll
  for (int ks = 0; ks < 16; ks++) s += P[(size_t)ks * 184320 + gid];
  s += hb[t];
  int b = bn >> 6, n = bn & 63;
  float val = (s - rb[n]) / (rw[n] + 1e-10f) * stdevA[bn] + meanA[bn];
  out[((size_t)(b * 720 + t)) * 64 + n] = val;
}

}  // namespace

extern "C" void kernel_launch(void* const* d_in, const int* in_sizes, int n_in,
                              void* d_out, int out_size, void* d_ws, size_t ws_size,
                              hipStream_t stream) {
  (void)in_sizes; (void)n_in; (void)out_size; (void)ws_size;
  const float* hist   = (const float*)d_in[0];
  const float* revw   = (const float*)d_in[5];
  const float* revb   = (const float*)d_in[6];
  const float* predw  = (const float*)d_in[7];
  const float* predb  = (const float*)d_in[8];
  const float* embw   = (const float*)d_in[9];
  const float* lnw    = (const float*)d_in[10];
  const float* lnb    = (const float*)d_in[11];
  const float* combw  = (const float*)d_in[12];
  const float* combb  = (const float*)d_in[13];
  const float* headw  = (const float*)d_in[14];
  const float* headb  = (const float*)d_in[15];
  const float* tmd_w1 = (const float*)d_in[16];
  const float* tmd_b1 = (const float*)d_in[17];
  const float* tmd_w2 = (const float*)d_in[18];
  const float* tmd_b2 = (const float*)d_in[19];
  const float* tmd_nw = (const float*)d_in[20];
  const float* tmd_nb = (const float*)d_in[21];
  const float* tmu_w1 = (const float*)d_in[22];
  const float* tmu_b1 = (const float*)d_in[23];
  const float* tmu_w2 = (const float*)d_in[24];
  const float* tmu_b2 = (const float*)d_in[25];
  const float* tmu_nw = (const float*)d_in[26];
  const float* tmu_nb = (const float*)d_in[27];
  const float* cmd_w1 = (const float*)d_in[28];
  const float* cmd_b1 = (const float*)d_in[29];
  const float* cmd_w2 = (const float*)d_in[30];
  const float* cmd_b2 = (const float*)d_in[31];
  const float* cmd_nw = (const float*)d_in[32];
  const float* cmd_nb = (const float*)d_in[33];
  const float* cmu_w1 = (const float*)d_in[34];
  const float* cmu_b1 = (const float*)d_in[35];
  const float* cmu_w2 = (const float*)d_in[36];
  const float* cmu_b2 = (const float*)d_in[37];
  const float* cmu_nw = (const float*)d_in[38];
  const float* cmu_nb = (const float*)d_in[39];

  // ---- workspace layout (no aliasing) ----
  float* ws = (float*)d_ws;
  float* meanA  = ws;                   // 256
  float* stdevA = meanA + 256;          // 256
  float* sA     = stdevA + 256;         // 256
  float* sB     = sA + 256;             // 256
  float* muX    = sB + 256;             // 23040
  float* rsX    = muX + 23040;          // 23040
  float* muP    = rsX + 23040;          // 23040
  float* rsP    = muP + 23040;          // 23040
  float* sqa    = rsP + 23040;          // 65536
  float* xbuf   = sqa + 65536;          // 368640
  unsigned short* xoldB = (unsigned short*)(xbuf + 368640);   // 90*256*256 bf16
  unsigned short* A0    = xoldB + 5898240;                    // 46080*256 bf16
  unsigned short* A1    = A0 + 11796480;
  unsigned short* B16   = A1 + 11796480;                      // 256*256*192 bf16
  unsigned short* Yb    = B16 + 12582912;                     // 256*256*180 bf16
  float* part           = (float*)(Yb + 11796480);            // 16*184320 fp32
  unsigned short* Xtb   = (unsigned short*)(part + 2949120);  // 256*46080 bf16
  unsigned short* WtAll = Xtb + 11796480;                     // 6 * 11796480 bf16
  unsigned short* WcAll = WtAll + 70778880;                   // 6 * 9437184 bf16
  unsigned short* WhAll = WcAll + 56623104;                   // 768*46080 bf16

  constexpr int TW = 180 * 256 * 256, TB = 180 * 256;
  constexpr int CW = 256 * 180 * 180, CB = 256 * 180;
  constexpr size_t TSTR = 11796480, CSTR = 9437184;

  // Single mixed launch (range/interleave splits both measured slower).
  convT_all_kernel<<<2048, 256, 0, stream>>>(
      tmd_w1 + TW, tmd_w2 + TW, tmu_w1 + TW, tmu_w2 + TW, tmu_w1, tmu_w2,
      cmd_w1 + CW, cmd_w2 + CW, cmu_w1 + CW, cmu_w2 + CW, cmu_w1, cmu_w2,
      headw, WtAll, WcAll, WhAll, 0, 1);

  revin_stats_kernel<<<4, 256, 0, stream>>>(hist, revw, revb, meanA, stdevA, sA, sB);
  pred_kernel<<<dim3(45, 4), 256, 0, stream>>>(hist, predw, predb, sA, sB, xbuf);
  embed_kernel<<<dim3(12, 256), 256, 0, stream>>>(xbuf, embw, A0, 0, nullptr, nullptr);
  embed_kernel<<<dim3(6, 256), 256, 0, stream>>>(hist, embw, xoldB, 1, muX, rsX);

  const float* tB1[3] = {tmd_b1 + TB, tmu_b1 + TB, tmu_b1};
  const float* tB2[3] = {tmd_b2 + TB, tmu_b2 + TB, tmu_b2};
  const float* tNW[3] = {tmd_nw + 256, tmu_nw + 256, tmu_nw};
  const float* tNB[3] = {tmd_nb + 256, tmu_nb + 256, tmu_nb};
  const float* cB1[3] = {cmd_b1 + CB, cmu_b1 + CB, cmu_b1};
  const float* cB2[3] = {cmd_b2 + CB, cmu_b2 + CB, cmu_b2};
  const float* cNW[3] = {cmd_nw + 256, cmu_nw + 256, cmu_nw};
  const float* cNB[3] = {cmd_nb + 256, cmu_nb + 256, cmu_nb};

  for (int li = 0; li < 3; li++) {
    temp_mfma_kernel<<<720, 256, 0, stream>>>(
        A0, A1, WtAll + (size_t)(2 * li) * TSTR, tB1[li],
        WtAll + (size_t)(2 * li + 1) * TSTR, tB2[li], tNW[li], tNB[li]);
    tr_AB_kernel<<<dim3(8, 256), 256, 0, stream>>>(A1, B16);
    chan_mfma_kernel<<<1024, 256, 0, stream>>>(
        B16, Yb, WcAll + (size_t)(2 * li) * CSTR, cB1[li],
        WcAll + (size_t)(2 * li + 1) * CSTR, cB2[li]);
    trLN_kernel<<<dim3(12, 256), 256, 0, stream>>>(Yb, A0, cNW[li], cNB[li],
                                                   combw, combb, li == 2 ? 1 : 0,
                                                   muP, rsP);
  }

  autocorr_kernel<<<1024, 128, 0, stream>>>(xoldB, A0, muX, rsX, muP, rsP, lnw, lnb, sqa);
  scale_tr_kernel<<<dim3(48, 256), 256, 0, stream>>>(A0, sqa, Xtb);
  head_mfma_kernel<<<768, 256, 0, stream>>>(Xtb, WhAll, part);
  final_kernel<<<720, 256, 0, stream>>>(part, headb, revw, revb, meanA, stdevA, (float*)d_out);
}